// Round 2
// baseline (422.974 us; speedup 1.0000x reference)
//
#include <hip/hip_runtime.h>
#include <math.h>

// Problem constants
#define BATCH   8
#define LSEQ    4096      // 64*64
#define CMODEL  128
#define DIN     256
#define NSTATE  16
#define RRANK   8
#define NCH     128       // chunks per sequence
#define TCH     32        // timesteps per chunk (NCH*TCH == LSEQ)

__device__ __forceinline__ float sigmoid_fast(float x) {
    return __builtin_amdgcn_rcpf(1.0f + __expf(-x));
}
__device__ __forceinline__ float silu_fast(float x) { return x * sigmoid_fast(x); }
__device__ __forceinline__ float softplus_fast(float x) {
    // log(1+e^x) = max(x,0) + log(1+e^-|x|); arg of log in (1,2] -> v_log ok
    return fmaxf(x, 0.0f) + __logf(1.0f + __expf(-fabsf(x)));
}

// ---------------------------------------------------------------------------
// K1: xz = x @ W_in ; split into xh_raw (cols 0..255) and z_silu = silu(z)
// x[b,l,c] = x_hsi[b,c,l].  Tile 64(l) x 64(j), K=128 in 2 chunks of 64.
// grid (512, 8), block 256
// ---------------------------------------------------------------------------
__global__ __launch_bounds__(256) void k1_gemm_in(
    const float* __restrict__ x_hsi, const float* __restrict__ W_in,
    float* __restrict__ xh_raw, float* __restrict__ z_silu)
{
    __shared__ float xs[64][64];   // xs[k][l]
    __shared__ float ws[64][64];   // ws[k][j]
    const int tid = threadIdx.x;
    const int R0  = blockIdx.x * 64;          // global row (b*L + l)
    const int b   = R0 >> 12;
    const int l0  = R0 & 4095;
    const int j0  = blockIdx.y * 64;
    const int tx  = tid & 15, ty = tid >> 4;

    float acc[4][4];
    #pragma unroll
    for (int i = 0; i < 4; ++i)
        #pragma unroll
        for (int j = 0; j < 4; ++j) acc[i][j] = 0.0f;

    for (int kc = 0; kc < 128; kc += 64) {
        #pragma unroll
        for (int it = 0; it < 4; ++it) {
            int idx4 = tid + it * 256;            // 1024 float4 per tile
            int c = idx4 >> 4, i4 = idx4 & 15;
            float4 v = *(const float4*)&x_hsi[((b * 128 + kc + c) << 12) + l0 + i4 * 4];
            *(float4*)&xs[c][i4 * 4] = v;
            float4 w = *(const float4*)&W_in[(kc + c) * 512 + j0 + i4 * 4];
            *(float4*)&ws[c][i4 * 4] = w;
        }
        __syncthreads();
        #pragma unroll 8
        for (int k = 0; k < 64; ++k) {
            float4 a  = *(const float4*)&xs[k][ty * 4];
            float4 bb = *(const float4*)&ws[k][tx * 4];
            float av[4] = {a.x, a.y, a.z, a.w};
            float bv[4] = {bb.x, bb.y, bb.z, bb.w};
            #pragma unroll
            for (int i = 0; i < 4; ++i)
                #pragma unroll
                for (int j = 0; j < 4; ++j) acc[i][j] = fmaf(av[i], bv[j], acc[i][j]);
        }
        __syncthreads();
    }

    const bool is_xh = (j0 < 256);
    #pragma unroll
    for (int i = 0; i < 4; ++i) {
        int gr = R0 + ty * 4 + i;
        float4 v = make_float4(acc[i][0], acc[i][1], acc[i][2], acc[i][3]);
        if (is_xh) {
            *(float4*)&xh_raw[gr * 256 + j0 + tx * 4] = v;
        } else {
            v.x = silu_fast(v.x); v.y = silu_fast(v.y);
            v.z = silu_fast(v.z); v.w = silu_fast(v.w);
            *(float4*)&z_silu[gr * 256 + (j0 - 256) + tx * 4] = v;
        }
    }
}

// ---------------------------------------------------------------------------
// K4: xdbl[row, 0:40] = conv_silu(xh_raw)[row,:] @ W_x   (conv inlined)
// thread = one row (b*L+l); W_x + conv params staged in LDS.
// grid 128, block 256
// ---------------------------------------------------------------------------
__global__ __launch_bounds__(256) void k4_xdbl(
    const float* __restrict__ xh_raw, const float* __restrict__ conv_w,
    const float* __restrict__ conv_b, const float* __restrict__ W_x,
    float* __restrict__ xdbl)
{
    __shared__ float wl[256 * 40];
    __shared__ float cw0[256], cw1[256], cbs[256];
    const int tid = threadIdx.x;
    #pragma unroll
    for (int it = 0; it < 10; ++it) {
        int i4 = tid + it * 256;                  // 2560 float4 = 10240 floats
        ((float4*)wl)[i4] = ((const float4*)W_x)[i4];
    }
    cw0[tid] = conv_w[2 * tid];
    cw1[tid] = conv_w[2 * tid + 1];
    cbs[tid] = conv_b[tid];
    __syncthreads();

    const int row = blockIdx.x * 256 + tid;
    const int l   = row & 4095;
    const bool has_prev = (l > 0);
    const float4* xr = (const float4*)&xh_raw[row * 256];
    const float4* xp = (const float4*)&xh_raw[(row - 1) * 256];

    float4 acc[10];
    #pragma unroll
    for (int m = 0; m < 10; ++m) acc[m] = make_float4(0.f, 0.f, 0.f, 0.f);

    #pragma unroll 4
    for (int k4 = 0; k4 < 64; ++k4) {
        float4 cur = xr[k4];
        float4 prv = has_prev ? xp[k4] : make_float4(0.f, 0.f, 0.f, 0.f);
        float cu[4] = {cur.x, cur.y, cur.z, cur.w};
        float pv[4] = {prv.x, prv.y, prv.z, prv.w};
        #pragma unroll
        for (int kk = 0; kk < 4; ++kk) {
            int d = k4 * 4 + kk;
            float pre = pv[kk] * cw0[d] + cu[kk] * cw1[d] + cbs[d];
            float v = silu_fast(pre);
            const float4* wr = (const float4*)&wl[d * 40];
            #pragma unroll
            for (int m = 0; m < 10; ++m) {
                float4 w = wr[m];
                acc[m].x = fmaf(v, w.x, acc[m].x);
                acc[m].y = fmaf(v, w.y, acc[m].y);
                acc[m].z = fmaf(v, w.z, acc[m].z);
                acc[m].w = fmaf(v, w.w, acc[m].w);
            }
        }
    }
    float4* outr = (float4*)&xdbl[row * 40];
    #pragma unroll
    for (int m = 0; m < 10; ++m) outr[m] = acc[m];
}

// ---------------------------------------------------------------------------
// Scan pass 1: per (b, chunk, d): local h (h_in=0) and decay product P.
// conv+silu and dt=softplus(dtlow@W_dt+b_dt) computed inline.
// P computed as exp(A[n]*sum(dt)) once per chunk (== per-step product).
// grid (NCH, BATCH), block 256 (thread = d)
// ---------------------------------------------------------------------------
__global__ __launch_bounds__(256) void k6_scan1(
    const float* __restrict__ xh_raw, const float* __restrict__ xdbl,
    const float* __restrict__ conv_w, const float* __restrict__ conv_b,
    const float* __restrict__ W_dt, const float* __restrict__ b_dt,
    const float* __restrict__ A_log,
    float* __restrict__ hend, float* __restrict__ Pprod)
{
    const int d = threadIdx.x;
    const int chunk = blockIdx.x;
    const int b = blockIdx.y;

    float A[16];
    #pragma unroll
    for (int q = 0; q < 4; ++q) {
        float4 al = *(const float4*)&A_log[d * 16 + q * 4];
        A[q*4+0] = -__expf(al.x); A[q*4+1] = -__expf(al.y);
        A[q*4+2] = -__expf(al.z); A[q*4+3] = -__expf(al.w);
    }
    float wdt[8];
    #pragma unroll
    for (int r = 0; r < 8; ++r) wdt[r] = W_dt[r * 256 + d];
    const float bdt = b_dt[d];
    const float w0 = conv_w[2 * d], w1 = conv_w[2 * d + 1], cb = conv_b[d];

    float h[16];
    #pragma unroll
    for (int n = 0; n < 16; ++n) h[n] = 0.f;
    float dtsum = 0.f;

    const int t0 = b * LSEQ + chunk * TCH;       // global row
    float prev = (chunk > 0) ? xh_raw[(t0 - 1) * 256 + d] : 0.f;

    #pragma unroll 2
    for (int tt = 0; tt < TCH; ++tt) {
        const int row = t0 + tt;
        float cur = xh_raw[row * 256 + d];
        float xcv = silu_fast(prev * w0 + cur * w1 + cb);
        prev = cur;

        const float4* bc4 = (const float4*)&xdbl[row * 40];
        float dl[8];
        *(float4*)&dl[0] = bc4[0]; *(float4*)&dl[4] = bc4[1];
        float dtr = bdt;
        #pragma unroll
        for (int r = 0; r < 8; ++r) dtr = fmaf(dl[r], wdt[r], dtr);
        float dtv = softplus_fast(dtr);
        dtsum += dtv;

        float Bt[16];
        *(float4*)&Bt[0]  = bc4[2]; *(float4*)&Bt[4]  = bc4[3];
        *(float4*)&Bt[8]  = bc4[4]; *(float4*)&Bt[12] = bc4[5];

        float dtx = dtv * xcv;
        #pragma unroll
        for (int n = 0; n < 16; ++n) {
            float dA = __expf(dtv * A[n]);
            h[n] = fmaf(dA, h[n], dtx * Bt[n]);
        }
    }

    const int base = ((b * NCH + chunk) * 256 + d) * 16;
    #pragma unroll
    for (int q = 0; q < 4; ++q) {
        *(float4*)&hend[base + q * 4] = make_float4(h[q*4], h[q*4+1], h[q*4+2], h[q*4+3]);
        float4 pv = make_float4(__expf(dtsum * A[q*4+0]), __expf(dtsum * A[q*4+1]),
                                __expf(dtsum * A[q*4+2]), __expf(dtsum * A[q*4+3]));
        *(float4*)&Pprod[base + q * 4] = pv;
    }
}

// ---------------------------------------------------------------------------
// Scan pass 2: sequential combine over chunks; thread = (b, d, n).
// hx holds hend on entry, hin on exit (in-place). Next chunk prefetched.
// grid 128, block 256
// ---------------------------------------------------------------------------
__global__ __launch_bounds__(256) void k7_combine(
    const float* __restrict__ Pp, float* __restrict__ hx)
{
    const int idx = blockIdx.x * 256 + threadIdx.x;   // b*4096 + d*16 + n
    const int b = idx >> 12;
    const int rem = idx & 4095;
    int o = ((b * NCH) << 12) + rem;
    float h = 0.f;
    float P = Pp[o], E = hx[o];
    for (int c = 0; c < NCH; ++c) {
        int on = o + 4096;
        float Pn = 0.f, En = 0.f;
        if (c < NCH - 1) { Pn = Pp[on]; En = hx[on]; }
        hx[o] = h;                       // state entering chunk c
        h = fmaf(P, h, E);
        P = Pn; E = En; o = on;
    }
}

// ---------------------------------------------------------------------------
// Scan pass 3: replay with correct h_in, emit y = (scan + xc*D) * z_silu
// zy holds z_silu on entry; overwritten in-place with y*silu(z).
// grid (NCH, BATCH), block 256
// ---------------------------------------------------------------------------
__global__ __launch_bounds__(256) void k8_scan2(
    const float* __restrict__ xh_raw, const float* __restrict__ xdbl,
    const float* __restrict__ conv_w, const float* __restrict__ conv_b,
    const float* __restrict__ W_dt, const float* __restrict__ b_dt,
    const float* __restrict__ A_log, const float* __restrict__ Dvec,
    const float* __restrict__ hin, float* __restrict__ zy)
{
    const int d = threadIdx.x;
    const int chunk = blockIdx.x;
    const int b = blockIdx.y;

    float A[16];
    #pragma unroll
    for (int q = 0; q < 4; ++q) {
        float4 al = *(const float4*)&A_log[d * 16 + q * 4];
        A[q*4+0] = -__expf(al.x); A[q*4+1] = -__expf(al.y);
        A[q*4+2] = -__expf(al.z); A[q*4+3] = -__expf(al.w);
    }
    float wdt[8];
    #pragma unroll
    for (int r = 0; r < 8; ++r) wdt[r] = W_dt[r * 256 + d];
    const float bdt = b_dt[d];
    const float w0 = conv_w[2 * d], w1 = conv_w[2 * d + 1], cb = conv_b[d];
    const float Dd = Dvec[d];

    float h[16];
    const int hbase = ((b * NCH + chunk) * 256 + d) * 16;
    #pragma unroll
    for (int q = 0; q < 4; ++q) {
        float4 hv = *(const float4*)&hin[hbase + q * 4];
        h[q*4+0] = hv.x; h[q*4+1] = hv.y; h[q*4+2] = hv.z; h[q*4+3] = hv.w;
    }

    const int t0 = b * LSEQ + chunk * TCH;
    float prev = (chunk > 0) ? xh_raw[(t0 - 1) * 256 + d] : 0.f;

    #pragma unroll 2
    for (int tt = 0; tt < TCH; ++tt) {
        const int row = t0 + tt;
        float cur = xh_raw[row * 256 + d];
        float xcv = silu_fast(prev * w0 + cur * w1 + cb);
        prev = cur;

        const float4* bc4 = (const float4*)&xdbl[row * 40];
        float dl[8];
        *(float4*)&dl[0] = bc4[0]; *(float4*)&dl[4] = bc4[1];
        float dtr = bdt;
        #pragma unroll
        for (int r = 0; r < 8; ++r) dtr = fmaf(dl[r], wdt[r], dtr);
        float dtv = softplus_fast(dtr);

        float Bt[16], Ct[16];
        *(float4*)&Bt[0]  = bc4[2]; *(float4*)&Bt[4]  = bc4[3];
        *(float4*)&Bt[8]  = bc4[4]; *(float4*)&Bt[12] = bc4[5];
        *(float4*)&Ct[0]  = bc4[6]; *(float4*)&Ct[4]  = bc4[7];
        *(float4*)&Ct[8]  = bc4[8]; *(float4*)&Ct[12] = bc4[9];

        float dtx = dtv * xcv;
        float yv = 0.f;
        #pragma unroll
        for (int n = 0; n < 16; ++n) {
            float dA = __expf(dtv * A[n]);
            h[n] = fmaf(dA, h[n], dtx * Bt[n]);
            yv = fmaf(h[n], Ct[n], yv);
        }
        yv = fmaf(Dd, xcv, yv);
        const int oidx = row * 256 + d;
        float zs = zy[oidx];
        zy[oidx] = yv * zs;
    }
}

// ---------------------------------------------------------------------------
// K9: out_mm[b,c,l] = sum_k y[b,l,k] * W_out[k,c]   (stores transposed)
// Tile 64(l) x 64(c), K=256 in 4 chunks. grid (512, 2), block 256
// ---------------------------------------------------------------------------
__global__ __launch_bounds__(256) void k9_gemm_out(
    const float* __restrict__ ybuf, const float* __restrict__ W_out,
    float* __restrict__ out_mm)
{
    __shared__ float ys[64][68];   // ys[k][l]
    __shared__ float wt[64][68];   // wt[k][c]
    const int tid = threadIdx.x;
    const int R0 = blockIdx.x * 64;
    const int b  = R0 >> 12;
    const int l0 = R0 & 4095;
    const int c0 = blockIdx.y * 64;
    const int tx = tid & 15, ty = tid >> 4;   // tx: l dim, ty: c dim

    float acc[4][4];  // [c][l]
    #pragma unroll
    for (int i = 0; i < 4; ++i)
        #pragma unroll
        for (int j = 0; j < 4; ++j) acc[i][j] = 0.0f;

    for (int kc = 0; kc < 256; kc += 64) {
        #pragma unroll
        for (int it = 0; it < 4; ++it) {
            int idx4 = tid + it * 256;
            int r = idx4 >> 4, q4 = idx4 & 15;
            float4 v = *(const float4*)&ybuf[(R0 + r) * 256 + kc + q4 * 4];
            ys[q4*4+0][r] = v.x; ys[q4*4+1][r] = v.y;
            ys[q4*4+2][r] = v.z; ys[q4*4+3][r] = v.w;
            float4 w = *(const float4*)&W_out[(kc + r) * 128 + c0 + q4 * 4];
            *(float4*)&wt[r][q4 * 4] = w;
        }
        __syncthreads();
        #pragma unroll 8
        for (int k = 0; k < 64; ++k) {
            float4 a  = *(const float4*)&ys[k][tx * 4];
            float4 bb = *(const float4*)&wt[k][ty * 4];
            float av[4] = {a.x, a.y, a.z, a.w};
            float bv[4] = {bb.x, bb.y, bb.z, bb.w};
            #pragma unroll
            for (int i = 0; i < 4; ++i)
                #pragma unroll
                for (int j = 0; j < 4; ++j) acc[i][j] = fmaf(bv[i], av[j], acc[i][j]);
        }
        __syncthreads();
    }
    #pragma unroll
    for (int i = 0; i < 4; ++i) {
        int c = c0 + ty * 4 + i;
        float4 v = make_float4(acc[i][0], acc[i][1], acc[i][2], acc[i][3]);
        *(float4*)&out_mm[(b * 128 + c) * 4096 + l0 + tx * 4] = v;
    }
}

// ---------------------------------------------------------------------------
// K10a: partial sums for GroupNorm. block = (b,g,slice of 16384 floats)
// grid 256, block 256
// ---------------------------------------------------------------------------
__global__ __launch_bounds__(256) void k10a_gnpart(
    const float* __restrict__ out_mm, float* __restrict__ part)
{
    const int bid = blockIdx.x;
    const int b = bid >> 5, g = (bid >> 3) & 3, s = bid & 7;
    const float* base = out_mm + (b * 128 + g * 32) * 4096 + s * 16384;
    const int tid = threadIdx.x;
    float sum = 0.f, ssq = 0.f;
    #pragma unroll 4
    for (int it = 0; it < 16; ++it) {
        float4 v = *(const float4*)&base[(tid + it * 256) * 4];
        sum += v.x + v.y + v.z + v.w;
        ssq += v.x*v.x + v.y*v.y + v.z*v.z + v.w*v.w;
    }
    #pragma unroll
    for (int off = 32; off > 0; off >>= 1) {
        sum += __shfl_down(sum, off, 64);
        ssq += __shfl_down(ssq, off, 64);
    }
    __shared__ float ls[8];
    const int wid = tid >> 6, lane = tid & 63;
    if (lane == 0) { ls[wid * 2] = sum; ls[wid * 2 + 1] = ssq; }
    __syncthreads();
    if (tid == 0) {
        float S = ls[0] + ls[2] + ls[4] + ls[6];
        float Q = ls[1] + ls[3] + ls[5] + ls[7];
        part[bid * 2]     = S;
        part[bid * 2 + 1] = Q;
    }
}

// K10b: finalize mean / rsqrt(var+eps) per (b,g). grid 1, block 64
__global__ void k10b_gnstat(const float* __restrict__ part, float* __restrict__ stat)
{
    const int tid = threadIdx.x;
    if (tid < 32) {
        float S = 0.f, Q = 0.f;
        for (int s = 0; s < 8; ++s) {
            S += part[(tid * 8 + s) * 2];
            Q += part[(tid * 8 + s) * 2 + 1];
        }
        const float inv_n = 1.0f / 131072.0f;
        float mean = S * inv_n;
        float var  = Q * inv_n - mean * mean;
        stat[tid * 2]     = mean;
        stat[tid * 2 + 1] = rsqrtf(var + 1e-5f);
    }
}

// K10c: apply GN + silu + residual. grid 4096, block 256
__global__ __launch_bounds__(256) void k10c_apply(
    const float* __restrict__ out_mm, const float* __restrict__ stat,
    const float* __restrict__ gamma, const float* __restrict__ beta,
    const float* __restrict__ x_hsi, float* __restrict__ out)
{
    const int idx4 = blockIdx.x * 256 + threadIdx.x;
    const int flat = idx4 * 4;
    const int c = (flat >> 12) & 127;
    const int b = flat >> 19;
    const int g = c >> 5;
    const float mean = stat[(b * 4 + g) * 2];
    const float inv  = stat[(b * 4 + g) * 2 + 1];
    const float ga = gamma[c], be = beta[c];
    float4 v = *(const float4*)&out_mm[flat];
    float4 r = *(const float4*)&x_hsi[flat];
    float o[4];
    float vv[4] = {v.x, v.y, v.z, v.w};
    float rr[4] = {r.x, r.y, r.z, r.w};
    #pragma unroll
    for (int q = 0; q < 4; ++q) {
        float xn = (vv[q] - mean) * inv;
        float gv = xn * ga + be;
        o[q] = silu_fast(gv) + rr[q];
    }
    *(float4*)&out[flat] = make_float4(o[0], o[1], o[2], o[3]);
}

// ---------------------------------------------------------------------------
extern "C" void kernel_launch(void* const* d_in, const int* in_sizes, int n_in,
                              void* d_out, int out_size, void* d_ws, size_t ws_size,
                              hipStream_t stream)
{
    const float* x_hsi  = (const float*)d_in[0];
    const float* W_in   = (const float*)d_in[1];
    const float* conv_w = (const float*)d_in[2];
    const float* conv_b = (const float*)d_in[3];
    const float* W_x    = (const float*)d_in[4];
    const float* W_dt   = (const float*)d_in[5];
    const float* b_dt   = (const float*)d_in[6];
    const float* A_log  = (const float*)d_in[7];
    const float* Dv     = (const float*)d_in[8];
    const float* W_out  = (const float*)d_in[9];
    const float* gnw    = (const float*)d_in[10];
    const float* gnb    = (const float*)d_in[11];

    float* ws = (float*)d_ws;
    float* xh_raw = ws + 0;            // 8,388,608
    float* zy     = ws + 8388608;      // 8,388,608  z_silu -> y (in-place)
    float* out_mm = ws + 16777216;     // 4,194,304
    float* xdbl   = ws + 20971520;     // 1,310,720  (dtlow 8 | B 16 | C 16)
    float* hx     = ws + 22282240;     // 4,194,304  hend -> hin (in-place)
    float* Pp     = ws + 26476544;     // 4,194,304
    float* part   = ws + 30670848;     // 512
    float* stat   = ws + 30671360;     // 64
    float* outp   = (float*)d_out;

    k1_gemm_in<<<dim3(512, 8), 256, 0, stream>>>(x_hsi, W_in, xh_raw, zy);
    k4_xdbl<<<128, 256, 0, stream>>>(xh_raw, conv_w, conv_b, W_x, xdbl);
    k6_scan1<<<dim3(NCH, BATCH), 256, 0, stream>>>(xh_raw, xdbl, conv_w, conv_b,
                                                   W_dt, b_dt, A_log, hx, Pp);
    k7_combine<<<128, 256, 0, stream>>>(Pp, hx);
    k8_scan2<<<dim3(NCH, BATCH), 256, 0, stream>>>(xh_raw, xdbl, conv_w, conv_b,
                                                   W_dt, b_dt, A_log, Dv, hx, zy);
    k9_gemm_out<<<dim3(512, 2), 256, 0, stream>>>(zy, W_out, out_mm);
    k10a_gnpart<<<256, 256, 0, stream>>>(out_mm, part);
    k10b_gnstat<<<1, 64, 0, stream>>>(part, stat);
    k10c_apply<<<4096, 256, 0, stream>>>(out_mm, stat, gnw, gnb, x_hsi, outp);
}

// Round 3
// 315.272 us; speedup vs baseline: 1.3416x; 1.3416x over previous
//
#include <hip/hip_runtime.h>
#include <math.h>

// Problem constants
#define BATCH   8
#define LSEQ    4096      // 64*64
#define CMODEL  128
#define DIN     256
#define NSTATE  16
#define RRANK   8
#define NCH     128       // chunks per sequence
#define TCH     32        // timesteps per chunk (NCH*TCH == LSEQ)

__device__ __forceinline__ float sigmoid_fast(float x) {
    return __builtin_amdgcn_rcpf(1.0f + __expf(-x));
}
__device__ __forceinline__ float silu_fast(float x) { return x * sigmoid_fast(x); }
__device__ __forceinline__ float softplus_fast(float x) {
    return fmaxf(x, 0.0f) + __logf(1.0f + __expf(-fabsf(x)));
}

// ---------------------------------------------------------------------------
// K1: xz = x @ W_in ; split into xh_raw (cols 0..255) and z_silu = silu(z)
// grid (512, 8), block 256
// ---------------------------------------------------------------------------
__global__ __launch_bounds__(256) void k1_gemm_in(
    const float* __restrict__ x_hsi, const float* __restrict__ W_in,
    float* __restrict__ xh_raw, float* __restrict__ z_silu)
{
    __shared__ float xs[64][64];   // xs[k][l]
    __shared__ float ws[64][64];   // ws[k][j]
    const int tid = threadIdx.x;
    const int R0  = blockIdx.x * 64;          // global row (b*L + l)
    const int b   = R0 >> 12;
    const int l0  = R0 & 4095;
    const int j0  = blockIdx.y * 64;
    const int tx  = tid & 15, ty = tid >> 4;

    float acc[4][4];
    #pragma unroll
    for (int i = 0; i < 4; ++i)
        #pragma unroll
        for (int j = 0; j < 4; ++j) acc[i][j] = 0.0f;

    for (int kc = 0; kc < 128; kc += 64) {
        #pragma unroll
        for (int it = 0; it < 4; ++it) {
            int idx4 = tid + it * 256;            // 1024 float4 per tile
            int c = idx4 >> 4, i4 = idx4 & 15;
            float4 v = *(const float4*)&x_hsi[((b * 128 + kc + c) << 12) + l0 + i4 * 4];
            *(float4*)&xs[c][i4 * 4] = v;
            float4 w = *(const float4*)&W_in[(kc + c) * 512 + j0 + i4 * 4];
            *(float4*)&ws[c][i4 * 4] = w;
        }
        __syncthreads();
        #pragma unroll 8
        for (int k = 0; k < 64; ++k) {
            float4 a  = *(const float4*)&xs[k][ty * 4];
            float4 bb = *(const float4*)&ws[k][tx * 4];
            float av[4] = {a.x, a.y, a.z, a.w};
            float bv[4] = {bb.x, bb.y, bb.z, bb.w};
            #pragma unroll
            for (int i = 0; i < 4; ++i)
                #pragma unroll
                for (int j = 0; j < 4; ++j) acc[i][j] = fmaf(av[i], bv[j], acc[i][j]);
        }
        __syncthreads();
    }

    const bool is_xh = (j0 < 256);
    #pragma unroll
    for (int i = 0; i < 4; ++i) {
        int gr = R0 + ty * 4 + i;
        float4 v = make_float4(acc[i][0], acc[i][1], acc[i][2], acc[i][3]);
        if (is_xh) {
            *(float4*)&xh_raw[gr * 256 + j0 + tx * 4] = v;
        } else {
            v.x = silu_fast(v.x); v.y = silu_fast(v.y);
            v.z = silu_fast(v.z); v.w = silu_fast(v.w);
            *(float4*)&z_silu[gr * 256 + (j0 - 256) + tx * 4] = v;
        }
    }
}

// ---------------------------------------------------------------------------
// K4 v3: xdbl = conv_silu(xh) @ W_x as tiled GEMM.
// Block: 128 rows x 40 cols, K=256 in 4 chunks of 64. conv+silu fused into
// LDS staging. Thread = 4 rows x 5 cols = 20 acc (~48 VGPR, no spill).
// grid 256, block 256
// ---------------------------------------------------------------------------
__global__ __launch_bounds__(256) void k4_xdbl(
    const float* __restrict__ xh_raw, const float* __restrict__ conv_w,
    const float* __restrict__ conv_b, const float* __restrict__ W_x,
    float* __restrict__ xdbl)
{
    __shared__ float xcs[128][68];     // xc tile, stride 68 (float4-aligned pad)
    __shared__ float wxs[64 * 40];     // W_x chunk
    __shared__ float cw0[256], cw1[256], cbs[256];
    const int tid = threadIdx.x;
    cw0[tid] = conv_w[2 * tid];
    cw1[tid] = conv_w[2 * tid + 1];
    cbs[tid] = conv_b[tid];

    const int R0 = blockIdx.x * 128;
    const int tc = tid & 7;            // col group: cols tc*5 .. tc*5+4
    const int tr = tid >> 3;           // row group: rows tr*4 .. tr*4+3

    float acc[4][5];
    #pragma unroll
    for (int i = 0; i < 4; ++i)
        #pragma unroll
        for (int j = 0; j < 5; ++j) acc[i][j] = 0.0f;

    for (int kc = 0; kc < 256; kc += 64) {
        __syncthreads();   // covers cw stage (first iter) + LDS reuse (later iters)
        // stage W_x chunk: rows kc..kc+63 contiguous = 2560 floats = 640 float4
        #pragma unroll
        for (int it = 0; it < 3; ++it) {
            int i4 = tid + it * 256;
            if (i4 < 640) ((float4*)wxs)[i4] = ((const float4*)&W_x[kc * 40])[i4];
        }
        // stage xc tile with conv + silu fused: 128 rows x 64 d
        #pragma unroll
        for (int it = 0; it < 8; ++it) {
            int idx = tid + it * 256;          // 0..2047
            int r = idx >> 4, q = idx & 15;
            int row = R0 + r;
            float4 cur = *(const float4*)&xh_raw[row * 256 + kc + q * 4];
            float4 prv = make_float4(0.f, 0.f, 0.f, 0.f);
            if ((row & 4095) != 0)
                prv = *(const float4*)&xh_raw[(row - 1) * 256 + kc + q * 4];
            int d = kc + q * 4;
            float4 o;
            o.x = silu_fast(prv.x * cw0[d+0] + cur.x * cw1[d+0] + cbs[d+0]);
            o.y = silu_fast(prv.y * cw0[d+1] + cur.y * cw1[d+1] + cbs[d+1]);
            o.z = silu_fast(prv.z * cw0[d+2] + cur.z * cw1[d+2] + cbs[d+2]);
            o.w = silu_fast(prv.w * cw0[d+3] + cur.w * cw1[d+3] + cbs[d+3]);
            *(float4*)&xcs[r][q * 4] = o;
        }
        __syncthreads();
        // compute: 20 FMA per k per thread
        #pragma unroll 2
        for (int k = 0; k < 64; ++k) {
            float w[5];
            #pragma unroll
            for (int j = 0; j < 5; ++j) w[j] = wxs[k * 40 + tc * 5 + j];
            #pragma unroll
            for (int i = 0; i < 4; ++i) {
                float a = xcs[tr * 4 + i][k];
                #pragma unroll
                for (int j = 0; j < 5; ++j) acc[i][j] = fmaf(a, w[j], acc[i][j]);
            }
        }
    }
    #pragma unroll
    for (int i = 0; i < 4; ++i) {
        int row = R0 + tr * 4 + i;
        #pragma unroll
        for (int j = 0; j < 5; ++j) xdbl[row * 40 + tc * 5 + j] = acc[i][j];
    }
}

// ---------------------------------------------------------------------------
// Scan pass 1: per (b, chunk, d): local h (h_in=0) and decay product P.
// grid (NCH, BATCH), block 256 (thread = d)
// ---------------------------------------------------------------------------
__global__ __launch_bounds__(256) void k6_scan1(
    const float* __restrict__ xh_raw, const float* __restrict__ xdbl,
    const float* __restrict__ conv_w, const float* __restrict__ conv_b,
    const float* __restrict__ W_dt, const float* __restrict__ b_dt,
    const float* __restrict__ A_log,
    float* __restrict__ hend, float* __restrict__ Pprod)
{
    const int d = threadIdx.x;
    const int chunk = blockIdx.x;
    const int b = blockIdx.y;

    float A[16];
    #pragma unroll
    for (int q = 0; q < 4; ++q) {
        float4 al = *(const float4*)&A_log[d * 16 + q * 4];
        A[q*4+0] = -__expf(al.x); A[q*4+1] = -__expf(al.y);
        A[q*4+2] = -__expf(al.z); A[q*4+3] = -__expf(al.w);
    }
    float wdt[8];
    #pragma unroll
    for (int r = 0; r < 8; ++r) wdt[r] = W_dt[r * 256 + d];
    const float bdt = b_dt[d];
    const float w0 = conv_w[2 * d], w1 = conv_w[2 * d + 1], cb = conv_b[d];

    float h[16];
    #pragma unroll
    for (int n = 0; n < 16; ++n) h[n] = 0.f;
    float dtsum = 0.f;

    const int t0 = b * LSEQ + chunk * TCH;
    float prev = (chunk > 0) ? xh_raw[(t0 - 1) * 256 + d] : 0.f;

    #pragma unroll 2
    for (int tt = 0; tt < TCH; ++tt) {
        const int row = t0 + tt;
        float cur = xh_raw[row * 256 + d];
        float xcv = silu_fast(prev * w0 + cur * w1 + cb);
        prev = cur;

        const float4* bc4 = (const float4*)&xdbl[row * 40];
        float dl[8];
        *(float4*)&dl[0] = bc4[0]; *(float4*)&dl[4] = bc4[1];
        float dtr = bdt;
        #pragma unroll
        for (int r = 0; r < 8; ++r) dtr = fmaf(dl[r], wdt[r], dtr);
        float dtv = softplus_fast(dtr);
        dtsum += dtv;

        float Bt[16];
        *(float4*)&Bt[0]  = bc4[2]; *(float4*)&Bt[4]  = bc4[3];
        *(float4*)&Bt[8]  = bc4[4]; *(float4*)&Bt[12] = bc4[5];

        float dtx = dtv * xcv;
        #pragma unroll
        for (int n = 0; n < 16; ++n) {
            float dA = __expf(dtv * A[n]);
            h[n] = fmaf(dA, h[n], dtx * Bt[n]);
        }
    }

    const int base = ((b * NCH + chunk) * 256 + d) * 16;
    #pragma unroll
    for (int q = 0; q < 4; ++q) {
        *(float4*)&hend[base + q * 4] = make_float4(h[q*4], h[q*4+1], h[q*4+2], h[q*4+3]);
        float4 pv = make_float4(__expf(dtsum * A[q*4+0]), __expf(dtsum * A[q*4+1]),
                                __expf(dtsum * A[q*4+2]), __expf(dtsum * A[q*4+3]));
        *(float4*)&Pprod[base + q * 4] = pv;
    }
}

// ---------------------------------------------------------------------------
// Scan pass 2: sequential combine over chunks; thread = (b, d, n).
// grid 128, block 256
// ---------------------------------------------------------------------------
__global__ __launch_bounds__(256) void k7_combine(
    const float* __restrict__ Pp, float* __restrict__ hx)
{
    const int idx = blockIdx.x * 256 + threadIdx.x;   // b*4096 + d*16 + n
    const int b = idx >> 12;
    const int rem = idx & 4095;
    int o = ((b * NCH) << 12) + rem;
    float h = 0.f;
    float P = Pp[o], E = hx[o];
    for (int c = 0; c < NCH; ++c) {
        int on = o + 4096;
        float Pn = 0.f, En = 0.f;
        if (c < NCH - 1) { Pn = Pp[on]; En = hx[on]; }
        hx[o] = h;                       // state entering chunk c
        h = fmaf(P, h, E);
        P = Pn; E = En; o = on;
    }
}

// ---------------------------------------------------------------------------
// Scan pass 3: replay with correct h_in, emit y = (scan + xc*D) * z_silu
// zy in-place: z_silu -> y. grid (NCH, BATCH), block 256
// ---------------------------------------------------------------------------
__global__ __launch_bounds__(256) void k8_scan2(
    const float* __restrict__ xh_raw, const float* __restrict__ xdbl,
    const float* __restrict__ conv_w, const float* __restrict__ conv_b,
    const float* __restrict__ W_dt, const float* __restrict__ b_dt,
    const float* __restrict__ A_log, const float* __restrict__ Dvec,
    const float* __restrict__ hin, float* __restrict__ zy)
{
    const int d = threadIdx.x;
    const int chunk = blockIdx.x;
    const int b = blockIdx.y;

    float A[16];
    #pragma unroll
    for (int q = 0; q < 4; ++q) {
        float4 al = *(const float4*)&A_log[d * 16 + q * 4];
        A[q*4+0] = -__expf(al.x); A[q*4+1] = -__expf(al.y);
        A[q*4+2] = -__expf(al.z); A[q*4+3] = -__expf(al.w);
    }
    float wdt[8];
    #pragma unroll
    for (int r = 0; r < 8; ++r) wdt[r] = W_dt[r * 256 + d];
    const float bdt = b_dt[d];
    const float w0 = conv_w[2 * d], w1 = conv_w[2 * d + 1], cb = conv_b[d];
    const float Dd = Dvec[d];

    float h[16];
    const int hbase = ((b * NCH + chunk) * 256 + d) * 16;
    #pragma unroll
    for (int q = 0; q < 4; ++q) {
        float4 hv = *(const float4*)&hin[hbase + q * 4];
        h[q*4+0] = hv.x; h[q*4+1] = hv.y; h[q*4+2] = hv.z; h[q*4+3] = hv.w;
    }

    const int t0 = b * LSEQ + chunk * TCH;
    float prev = (chunk > 0) ? xh_raw[(t0 - 1) * 256 + d] : 0.f;

    #pragma unroll 2
    for (int tt = 0; tt < TCH; ++tt) {
        const int row = t0 + tt;
        float cur = xh_raw[row * 256 + d];
        float xcv = silu_fast(prev * w0 + cur * w1 + cb);
        prev = cur;

        const float4* bc4 = (const float4*)&xdbl[row * 40];
        float dl[8];
        *(float4*)&dl[0] = bc4[0]; *(float4*)&dl[4] = bc4[1];
        float dtr = bdt;
        #pragma unroll
        for (int r = 0; r < 8; ++r) dtr = fmaf(dl[r], wdt[r], dtr);
        float dtv = softplus_fast(dtr);

        float Bt[16], Ct[16];
        *(float4*)&Bt[0]  = bc4[2]; *(float4*)&Bt[4]  = bc4[3];
        *(float4*)&Bt[8]  = bc4[4]; *(float4*)&Bt[12] = bc4[5];
        *(float4*)&Ct[0]  = bc4[6]; *(float4*)&Ct[4]  = bc4[7];
        *(float4*)&Ct[8]  = bc4[8]; *(float4*)&Ct[12] = bc4[9];

        float dtx = dtv * xcv;
        float yv = 0.f;
        #pragma unroll
        for (int n = 0; n < 16; ++n) {
            float dA = __expf(dtv * A[n]);
            h[n] = fmaf(dA, h[n], dtx * Bt[n]);
            yv = fmaf(h[n], Ct[n], yv);
        }
        yv = fmaf(Dd, xcv, yv);
        const int oidx = row * 256 + d;
        float zs = zy[oidx];
        zy[oidx] = yv * zs;
    }
}

// ---------------------------------------------------------------------------
// K9: out_mm[b,c,l] = sum_k y[b,l,k] * W_out[k,c]   (stores transposed)
// grid (512, 2), block 256
// ---------------------------------------------------------------------------
__global__ __launch_bounds__(256) void k9_gemm_out(
    const float* __restrict__ ybuf, const float* __restrict__ W_out,
    float* __restrict__ out_mm)
{
    __shared__ float ys[64][68];   // ys[k][l]
    __shared__ float wt[64][68];   // wt[k][c]
    const int tid = threadIdx.x;
    const int R0 = blockIdx.x * 64;
    const int b  = R0 >> 12;
    const int l0 = R0 & 4095;
    const int c0 = blockIdx.y * 64;
    const int tx = tid & 15, ty = tid >> 4;   // tx: l dim, ty: c dim

    float acc[4][4];  // [c][l]
    #pragma unroll
    for (int i = 0; i < 4; ++i)
        #pragma unroll
        for (int j = 0; j < 4; ++j) acc[i][j] = 0.0f;

    for (int kc = 0; kc < 256; kc += 64) {
        #pragma unroll
        for (int it = 0; it < 4; ++it) {
            int idx4 = tid + it * 256;
            int r = idx4 >> 4, q4 = idx4 & 15;
            float4 v = *(const float4*)&ybuf[(R0 + r) * 256 + kc + q4 * 4];
            ys[q4*4+0][r] = v.x; ys[q4*4+1][r] = v.y;
            ys[q4*4+2][r] = v.z; ys[q4*4+3][r] = v.w;
            float4 w = *(const float4*)&W_out[(kc + r) * 128 + c0 + q4 * 4];
            *(float4*)&wt[r][q4 * 4] = w;
        }
        __syncthreads();
        #pragma unroll 8
        for (int k = 0; k < 64; ++k) {
            float4 a  = *(const float4*)&ys[k][tx * 4];
            float4 bb = *(const float4*)&wt[k][ty * 4];
            float av[4] = {a.x, a.y, a.z, a.w};
            float bv[4] = {bb.x, bb.y, bb.z, bb.w};
            #pragma unroll
            for (int i = 0; i < 4; ++i)
                #pragma unroll
                for (int j = 0; j < 4; ++j) acc[i][j] = fmaf(bv[i], av[j], acc[i][j]);
        }
        __syncthreads();
    }
    #pragma unroll
    for (int i = 0; i < 4; ++i) {
        int c = c0 + ty * 4 + i;
        float4 v = make_float4(acc[i][0], acc[i][1], acc[i][2], acc[i][3]);
        *(float4*)&out_mm[(b * 128 + c) * 4096 + l0 + tx * 4] = v;
    }
}

// ---------------------------------------------------------------------------
// K10a: partial sums for GroupNorm. grid 256, block 256
// ---------------------------------------------------------------------------
__global__ __launch_bounds__(256) void k10a_gnpart(
    const float* __restrict__ out_mm, float* __restrict__ part)
{
    const int bid = blockIdx.x;
    const int b = bid >> 5, g = (bid >> 3) & 3, s = bid & 7;
    const float* base = out_mm + (b * 128 + g * 32) * 4096 + s * 16384;
    const int tid = threadIdx.x;
    float sum = 0.f, ssq = 0.f;
    #pragma unroll 4
    for (int it = 0; it < 16; ++it) {
        float4 v = *(const float4*)&base[(tid + it * 256) * 4];
        sum += v.x + v.y + v.z + v.w;
        ssq += v.x*v.x + v.y*v.y + v.z*v.z + v.w*v.w;
    }
    #pragma unroll
    for (int off = 32; off > 0; off >>= 1) {
        sum += __shfl_down(sum, off, 64);
        ssq += __shfl_down(ssq, off, 64);
    }
    __shared__ float ls[8];
    const int wid = tid >> 6, lane = tid & 63;
    if (lane == 0) { ls[wid * 2] = sum; ls[wid * 2 + 1] = ssq; }
    __syncthreads();
    if (tid == 0) {
        float S = ls[0] + ls[2] + ls[4] + ls[6];
        float Q = ls[1] + ls[3] + ls[5] + ls[7];
        part[bid * 2]     = S;
        part[bid * 2 + 1] = Q;
    }
}

// K10b: finalize mean / rsqrt(var+eps) per (b,g). grid 1, block 64
__global__ void k10b_gnstat(const float* __restrict__ part, float* __restrict__ stat)
{
    const int tid = threadIdx.x;
    if (tid < 32) {
        float S = 0.f, Q = 0.f;
        for (int s = 0; s < 8; ++s) {
            S += part[(tid * 8 + s) * 2];
            Q += part[(tid * 8 + s) * 2 + 1];
        }
        const float inv_n = 1.0f / 131072.0f;
        float mean = S * inv_n;
        float var  = Q * inv_n - mean * mean;
        stat[tid * 2]     = mean;
        stat[tid * 2 + 1] = rsqrtf(var + 1e-5f);
    }
}

// K10c: apply GN + silu + residual. grid 4096, block 256
__global__ __launch_bounds__(256) void k10c_apply(
    const float* __restrict__ out_mm, const float* __restrict__ stat,
    const float* __restrict__ gamma, const float* __restrict__ beta,
    const float* __restrict__ x_hsi, float* __restrict__ out)
{
    const int idx4 = blockIdx.x * 256 + threadIdx.x;
    const int flat = idx4 * 4;
    const int c = (flat >> 12) & 127;
    const int b = flat >> 19;
    const int g = c >> 5;
    const float mean = stat[(b * 4 + g) * 2];
    const float inv  = stat[(b * 4 + g) * 2 + 1];
    const float ga = gamma[c], be = beta[c];
    float4 v = *(const float4*)&out_mm[flat];
    float4 r = *(const float4*)&x_hsi[flat];
    float o[4];
    float vv[4] = {v.x, v.y, v.z, v.w};
    float rr[4] = {r.x, r.y, r.z, r.w};
    #pragma unroll
    for (int q = 0; q < 4; ++q) {
        float xn = (vv[q] - mean) * inv;
        float gv = xn * ga + be;
        o[q] = silu_fast(gv) + rr[q];
    }
    *(float4*)&out[flat] = make_float4(o[0], o[1], o[2], o[3]);
}

// ---------------------------------------------------------------------------
extern "C" void kernel_launch(void* const* d_in, const int* in_sizes, int n_in,
                              void* d_out, int out_size, void* d_ws, size_t ws_size,
                              hipStream_t stream)
{
    const float* x_hsi  = (const float*)d_in[0];
    const float* W_in   = (const float*)d_in[1];
    const float* conv_w = (const float*)d_in[2];
    const float* conv_b = (const float*)d_in[3];
    const float* W_x    = (const float*)d_in[4];
    const float* W_dt   = (const float*)d_in[5];
    const float* b_dt   = (const float*)d_in[6];
    const float* A_log  = (const float*)d_in[7];
    const float* Dv     = (const float*)d_in[8];
    const float* W_out  = (const float*)d_in[9];
    const float* gnw    = (const float*)d_in[10];
    const float* gnb    = (const float*)d_in[11];

    float* ws = (float*)d_ws;
    float* xh_raw = ws + 0;            // 8,388,608
    float* zy     = ws + 8388608;      // 8,388,608  z_silu -> y (in-place)
    float* out_mm = ws + 16777216;     // 4,194,304
    float* xdbl   = ws + 20971520;     // 1,310,720
    float* hx     = ws + 22282240;     // 4,194,304  hend -> hin (in-place)
    float* Pp     = ws + 26476544;     // 4,194,304
    float* part   = ws + 30670848;     // 512
    float* stat   = ws + 30671360;     // 64
    float* outp   = (float*)d_out;

    k1_gemm_in<<<dim3(512, 8), 256, 0, stream>>>(x_hsi, W_in, xh_raw, zy);
    k4_xdbl<<<256, 256, 0, stream>>>(xh_raw, conv_w, conv_b, W_x, xdbl);
    k6_scan1<<<dim3(NCH, BATCH), 256, 0, stream>>>(xh_raw, xdbl, conv_w, conv_b,
                                                   W_dt, b_dt, A_log, hx, Pp);
    k7_combine<<<128, 256, 0, stream>>>(Pp, hx);
    k8_scan2<<<dim3(NCH, BATCH), 256, 0, stream>>>(xh_raw, xdbl, conv_w, conv_b,
                                                   W_dt, b_dt, A_log, Dv, hx, zy);
    k9_gemm_out<<<dim3(512, 2), 256, 0, stream>>>(zy, W_out, out_mm);
    k10a_gnpart<<<256, 256, 0, stream>>>(out_mm, part);
    k10b_gnstat<<<1, 64, 0, stream>>>(part, stat);
    k10c_apply<<<4096, 256, 0, stream>>>(out_mm, stat, gnw, gnb, x_hsi, outp);
}

// Round 4
// 288.898 us; speedup vs baseline: 1.4641x; 1.0913x over previous
//
#include <hip/hip_runtime.h>
#include <math.h>

// Problem constants
#define BATCH   8
#define LSEQ    4096      // 64*64
#define CMODEL  128
#define DIN     256
#define NSTATE  16
#define RRANK   8
#define NCH     128       // chunks per sequence
#define TCH     32        // timesteps per chunk (NCH*TCH == LSEQ)

__device__ __forceinline__ float sigmoid_fast(float x) {
    return __builtin_amdgcn_rcpf(1.0f + __expf(-x));
}
__device__ __forceinline__ float silu_fast(float x) { return x * sigmoid_fast(x); }
__device__ __forceinline__ float softplus_fast(float x) {
    return fmaxf(x, 0.0f) + __logf(1.0f + __expf(-fabsf(x)));
}

// Compute dA[n] = exp(dtv*A[n]) for n=0..15. If A[n] == (n+1)*A[0] (the
// A_log = log(arange(1..16)) structure), use 1 exp + log-depth mul chain.
__device__ __forceinline__ void dA_powers(float dtv, const float* A, bool fast,
                                          float* dA)
{
    if (fast) {
        float e1 = __expf(dtv * A[0]);
        float e2 = e1 * e1;
        float e4 = e2 * e2;
        float e8 = e4 * e4;
        dA[0] = e1;        dA[1] = e2;        dA[2] = e2 * e1;   dA[3] = e4;
        dA[4] = e4 * e1;   dA[5] = e4 * e2;   dA[6] = e4 * dA[2]; dA[7] = e8;
        dA[8] = e8 * e1;   dA[9] = e8 * e2;   dA[10] = e8 * dA[2]; dA[11] = e8 * e4;
        dA[12] = e8 * dA[4]; dA[13] = e8 * dA[5]; dA[14] = e8 * dA[6]; dA[15] = e8 * e8;
    } else {
        #pragma unroll
        for (int n = 0; n < 16; ++n) dA[n] = __expf(dtv * A[n]);
    }
}

// ---------------------------------------------------------------------------
// K1: xz = x @ W_in ; 128x128 tile, 8x8 acc/thread, K=128 in chunks of 32.
// ty -> m(rows, 2x4), tx -> n(cols, 2x4, lane-fast for coalesced C writes).
// grid (256, 4), block 256
// ---------------------------------------------------------------------------
__global__ __launch_bounds__(256) void k1_gemm_in(
    const float* __restrict__ x_hsi, const float* __restrict__ W_in,
    float* __restrict__ xh_raw, float* __restrict__ z_silu)
{
    __shared__ float As[32][128];   // [k][m]
    __shared__ float Bs[32][128];   // [k][n]
    const int tid = threadIdx.x;
    const int R0  = blockIdx.x * 128;         // global row (b*L + l)
    const int b   = R0 >> 12;
    const int l0  = R0 & 4095;
    const int j0  = blockIdx.y * 128;
    const int tx  = tid & 15, ty = tid >> 4;

    float acc[8][8];
    #pragma unroll
    for (int i = 0; i < 8; ++i)
        #pragma unroll
        for (int j = 0; j < 8; ++j) acc[i][j] = 0.0f;

    for (int kc = 0; kc < 128; kc += 32) {
        #pragma unroll
        for (int it = 0; it < 4; ++it) {
            int idx4 = tid + it * 256;          // 0..1023
            int k = idx4 >> 5, m4 = idx4 & 31;
            float4 v = *(const float4*)&x_hsi[((b * 128 + kc + k) << 12) + l0 + m4 * 4];
            *(float4*)&As[k][m4 * 4] = v;
            float4 w = *(const float4*)&W_in[(kc + k) * 512 + j0 + m4 * 4];
            *(float4*)&Bs[k][m4 * 4] = w;
        }
        __syncthreads();
        #pragma unroll 2
        for (int k = 0; k < 32; ++k) {
            float4 a0 = *(const float4*)&As[k][ty * 4];
            float4 a1 = *(const float4*)&As[k][64 + ty * 4];
            float4 b0 = *(const float4*)&Bs[k][tx * 4];
            float4 b1 = *(const float4*)&Bs[k][64 + tx * 4];
            float am[8] = {a0.x, a0.y, a0.z, a0.w, a1.x, a1.y, a1.z, a1.w};
            float bn[8] = {b0.x, b0.y, b0.z, b0.w, b1.x, b1.y, b1.z, b1.w};
            #pragma unroll
            for (int i = 0; i < 8; ++i)
                #pragma unroll
                for (int j = 0; j < 8; ++j) acc[i][j] = fmaf(am[i], bn[j], acc[i][j]);
        }
        __syncthreads();
    }

    const bool is_xh = (j0 < 256);
    #pragma unroll
    for (int i = 0; i < 8; ++i) {
        int m = (i < 4) ? (ty * 4 + i) : (64 + ty * 4 + i - 4);
        int gr = R0 + m;
        #pragma unroll
        for (int jh = 0; jh < 2; ++jh) {
            float4 v = make_float4(acc[i][jh*4+0], acc[i][jh*4+1],
                                   acc[i][jh*4+2], acc[i][jh*4+3]);
            int col = j0 + jh * 64 + tx * 4;
            if (is_xh) {
                *(float4*)&xh_raw[gr * 256 + col] = v;
            } else {
                v.x = silu_fast(v.x); v.y = silu_fast(v.y);
                v.z = silu_fast(v.z); v.w = silu_fast(v.w);
                *(float4*)&z_silu[gr * 256 + col - 256] = v;
            }
        }
    }
}

// ---------------------------------------------------------------------------
// K4: xdbl = conv_silu(xh) @ W_x tiled GEMM (unchanged from round 3).
// grid 256, block 256
// ---------------------------------------------------------------------------
__global__ __launch_bounds__(256) void k4_xdbl(
    const float* __restrict__ xh_raw, const float* __restrict__ conv_w,
    const float* __restrict__ conv_b, const float* __restrict__ W_x,
    float* __restrict__ xdbl)
{
    __shared__ float xcs[128][68];
    __shared__ float wxs[64 * 40];
    __shared__ float cw0[256], cw1[256], cbs[256];
    const int tid = threadIdx.x;
    cw0[tid] = conv_w[2 * tid];
    cw1[tid] = conv_w[2 * tid + 1];
    cbs[tid] = conv_b[tid];

    const int R0 = blockIdx.x * 128;
    const int tc = tid & 7;
    const int tr = tid >> 3;

    float acc[4][5];
    #pragma unroll
    for (int i = 0; i < 4; ++i)
        #pragma unroll
        for (int j = 0; j < 5; ++j) acc[i][j] = 0.0f;

    for (int kc = 0; kc < 256; kc += 64) {
        __syncthreads();
        #pragma unroll
        for (int it = 0; it < 3; ++it) {
            int i4 = tid + it * 256;
            if (i4 < 640) ((float4*)wxs)[i4] = ((const float4*)&W_x[kc * 40])[i4];
        }
        #pragma unroll
        for (int it = 0; it < 8; ++it) {
            int idx = tid + it * 256;
            int r = idx >> 4, q = idx & 15;
            int row = R0 + r;
            float4 cur = *(const float4*)&xh_raw[row * 256 + kc + q * 4];
            float4 prv = make_float4(0.f, 0.f, 0.f, 0.f);
            if ((row & 4095) != 0)
                prv = *(const float4*)&xh_raw[(row - 1) * 256 + kc + q * 4];
            int d = kc + q * 4;
            float4 o;
            o.x = silu_fast(prv.x * cw0[d+0] + cur.x * cw1[d+0] + cbs[d+0]);
            o.y = silu_fast(prv.y * cw0[d+1] + cur.y * cw1[d+1] + cbs[d+1]);
            o.z = silu_fast(prv.z * cw0[d+2] + cur.z * cw1[d+2] + cbs[d+2]);
            o.w = silu_fast(prv.w * cw0[d+3] + cur.w * cw1[d+3] + cbs[d+3]);
            *(float4*)&xcs[r][q * 4] = o;
        }
        __syncthreads();
        #pragma unroll 2
        for (int k = 0; k < 64; ++k) {
            float w[5];
            #pragma unroll
            for (int j = 0; j < 5; ++j) w[j] = wxs[k * 40 + tc * 5 + j];
            #pragma unroll
            for (int i = 0; i < 4; ++i) {
                float a = xcs[tr * 4 + i][k];
                #pragma unroll
                for (int j = 0; j < 5; ++j) acc[i][j] = fmaf(a, w[j], acc[i][j]);
            }
        }
    }
    #pragma unroll
    for (int i = 0; i < 4; ++i) {
        int row = R0 + tr * 4 + i;
        #pragma unroll
        for (int j = 0; j < 5; ++j) xdbl[row * 40 + tc * 5 + j] = acc[i][j];
    }
}

// ---------------------------------------------------------------------------
// Scan pass 1: local h + decay product P. xdbl chunk staged in LDS,
// dA via 1-exp power chain. grid (NCH, BATCH), block 256
// ---------------------------------------------------------------------------
__global__ __launch_bounds__(256) void k6_scan1(
    const float* __restrict__ xh_raw, const float* __restrict__ xdbl,
    const float* __restrict__ conv_w, const float* __restrict__ conv_b,
    const float* __restrict__ W_dt, const float* __restrict__ b_dt,
    const float* __restrict__ A_log,
    float* __restrict__ hend, float* __restrict__ Pprod)
{
    __shared__ float xd[TCH * 40];
    const int d = threadIdx.x;
    const int chunk = blockIdx.x;
    const int b = blockIdx.y;
    const int t0 = b * LSEQ + chunk * TCH;

    // stage xdbl rows for this chunk: 32*40 = 1280 floats = 320 float4
    {
        const float4* src = (const float4*)&xdbl[t0 * 40];
        if (d < 256) ((float4*)xd)[d] = src[d];
        int i2 = d + 256;
        if (i2 < 320) ((float4*)xd)[i2] = src[i2];
    }

    float A[16];
    #pragma unroll
    for (int q = 0; q < 4; ++q) {
        float4 al = *(const float4*)&A_log[d * 16 + q * 4];
        A[q*4+0] = -__expf(al.x); A[q*4+1] = -__expf(al.y);
        A[q*4+2] = -__expf(al.z); A[q*4+3] = -__expf(al.w);
    }
    bool fast = true;
    #pragma unroll
    for (int n = 1; n < 16; ++n)
        fast = fast && (fabsf(A[n] - (n + 1) * A[0]) <= 1e-4f * fabsf(A[n]) + 1e-7f);

    float wdt[8];
    #pragma unroll
    for (int r = 0; r < 8; ++r) wdt[r] = W_dt[r * 256 + d];
    const float bdt = b_dt[d];
    const float w0 = conv_w[2 * d], w1 = conv_w[2 * d + 1], cb = conv_b[d];

    float h[16];
    #pragma unroll
    for (int n = 0; n < 16; ++n) h[n] = 0.f;
    float dtsum = 0.f;

    float prev = (chunk > 0) ? xh_raw[(t0 - 1) * 256 + d] : 0.f;
    __syncthreads();

    #pragma unroll 2
    for (int tt = 0; tt < TCH; ++tt) {
        const int row = t0 + tt;
        float cur = xh_raw[row * 256 + d];
        float xcv = silu_fast(prev * w0 + cur * w1 + cb);
        prev = cur;

        const float* xr = &xd[tt * 40];
        float dl[8];
        *(float4*)&dl[0] = *(const float4*)&xr[0];
        *(float4*)&dl[4] = *(const float4*)&xr[4];
        float dtr = bdt;
        #pragma unroll
        for (int r = 0; r < 8; ++r) dtr = fmaf(dl[r], wdt[r], dtr);
        float dtv = softplus_fast(dtr);
        dtsum += dtv;

        float Bt[16];
        #pragma unroll
        for (int q = 0; q < 4; ++q)
            *(float4*)&Bt[q * 4] = *(const float4*)&xr[8 + q * 4];

        float dA[16];
        dA_powers(dtv, A, fast, dA);
        float dtx = dtv * xcv;
        #pragma unroll
        for (int n = 0; n < 16; ++n)
            h[n] = fmaf(dA[n], h[n], dtx * Bt[n]);
    }

    float P[16];
    dA_powers(dtsum, A, fast, P);
    const int base = ((b * NCH + chunk) * 256 + d) * 16;
    #pragma unroll
    for (int q = 0; q < 4; ++q) {
        *(float4*)&hend[base + q * 4] = make_float4(h[q*4], h[q*4+1], h[q*4+2], h[q*4+3]);
        *(float4*)&Pprod[base + q * 4] = make_float4(P[q*4], P[q*4+1], P[q*4+2], P[q*4+3]);
    }
}

// ---------------------------------------------------------------------------
// Scan pass 2: sequential combine; hx: hend -> hin in-place. grid 128x256
// ---------------------------------------------------------------------------
__global__ __launch_bounds__(256) void k7_combine(
    const float* __restrict__ Pp, float* __restrict__ hx)
{
    const int idx = blockIdx.x * 256 + threadIdx.x;   // b*4096 + d*16 + n
    const int b = idx >> 12;
    const int rem = idx & 4095;
    int o = ((b * NCH) << 12) + rem;
    float h = 0.f;
    float P = Pp[o], E = hx[o];
    for (int c = 0; c < NCH; ++c) {
        int on = o + 4096;
        float Pn = 0.f, En = 0.f;
        if (c < NCH - 1) { Pn = Pp[on]; En = hx[on]; }
        hx[o] = h;
        h = fmaf(P, h, E);
        P = Pn; E = En; o = on;
    }
}

// ---------------------------------------------------------------------------
// Scan pass 3: replay with h_in, y = (scan + xc*D) * z_silu, in-place zy.
// grid (NCH, BATCH), block 256
// ---------------------------------------------------------------------------
__global__ __launch_bounds__(256) void k8_scan2(
    const float* __restrict__ xh_raw, const float* __restrict__ xdbl,
    const float* __restrict__ conv_w, const float* __restrict__ conv_b,
    const float* __restrict__ W_dt, const float* __restrict__ b_dt,
    const float* __restrict__ A_log, const float* __restrict__ Dvec,
    const float* __restrict__ hin, float* __restrict__ zy)
{
    __shared__ float xd[TCH * 40];
    const int d = threadIdx.x;
    const int chunk = blockIdx.x;
    const int b = blockIdx.y;
    const int t0 = b * LSEQ + chunk * TCH;

    {
        const float4* src = (const float4*)&xdbl[t0 * 40];
        if (d < 256) ((float4*)xd)[d] = src[d];
        int i2 = d + 256;
        if (i2 < 320) ((float4*)xd)[i2] = src[i2];
    }

    float A[16];
    #pragma unroll
    for (int q = 0; q < 4; ++q) {
        float4 al = *(const float4*)&A_log[d * 16 + q * 4];
        A[q*4+0] = -__expf(al.x); A[q*4+1] = -__expf(al.y);
        A[q*4+2] = -__expf(al.z); A[q*4+3] = -__expf(al.w);
    }
    bool fast = true;
    #pragma unroll
    for (int n = 1; n < 16; ++n)
        fast = fast && (fabsf(A[n] - (n + 1) * A[0]) <= 1e-4f * fabsf(A[n]) + 1e-7f);

    float wdt[8];
    #pragma unroll
    for (int r = 0; r < 8; ++r) wdt[r] = W_dt[r * 256 + d];
    const float bdt = b_dt[d];
    const float w0 = conv_w[2 * d], w1 = conv_w[2 * d + 1], cb = conv_b[d];
    const float Dd = Dvec[d];

    float h[16];
    const int hbase = ((b * NCH + chunk) * 256 + d) * 16;
    #pragma unroll
    for (int q = 0; q < 4; ++q) {
        float4 hv = *(const float4*)&hin[hbase + q * 4];
        h[q*4+0] = hv.x; h[q*4+1] = hv.y; h[q*4+2] = hv.z; h[q*4+3] = hv.w;
    }

    float prev = (chunk > 0) ? xh_raw[(t0 - 1) * 256 + d] : 0.f;
    __syncthreads();

    #pragma unroll 2
    for (int tt = 0; tt < TCH; ++tt) {
        const int row = t0 + tt;
        float cur = xh_raw[row * 256 + d];
        float xcv = silu_fast(prev * w0 + cur * w1 + cb);
        prev = cur;

        const float* xr = &xd[tt * 40];
        float dl[8];
        *(float4*)&dl[0] = *(const float4*)&xr[0];
        *(float4*)&dl[4] = *(const float4*)&xr[4];
        float dtr = bdt;
        #pragma unroll
        for (int r = 0; r < 8; ++r) dtr = fmaf(dl[r], wdt[r], dtr);
        float dtv = softplus_fast(dtr);

        float Bt[16], Ct[16];
        #pragma unroll
        for (int q = 0; q < 4; ++q) {
            *(float4*)&Bt[q * 4] = *(const float4*)&xr[8 + q * 4];
            *(float4*)&Ct[q * 4] = *(const float4*)&xr[24 + q * 4];
        }

        float dA[16];
        dA_powers(dtv, A, fast, dA);
        float dtx = dtv * xcv;
        float yv = 0.f;
        #pragma unroll
        for (int n = 0; n < 16; ++n) {
            h[n] = fmaf(dA[n], h[n], dtx * Bt[n]);
            yv = fmaf(h[n], Ct[n], yv);
        }
        yv = fmaf(Dd, xcv, yv);
        const int oidx = row * 256 + d;
        float zs = zy[oidx];
        zy[oidx] = yv * zs;
    }
}

// ---------------------------------------------------------------------------
// K9: out_mm[b,c,l] = sum_k y[b,l,k] * W_out[k,c]  (transposed store)
// 128(l) x 128(c) tile, 8x8 acc, K=256 in chunks of 32.
// tx -> m(l, lane-fast for coalesced store), ty -> n(c). grid 256, block 256
// ---------------------------------------------------------------------------
__global__ __launch_bounds__(256) void k9_gemm_out(
    const float* __restrict__ ybuf, const float* __restrict__ W_out,
    float* __restrict__ out_mm)
{
    __shared__ float ys[32][132];   // [k][m], pad to 132 (16B-aligned rows)
    __shared__ float wt[32][128];   // [k][n]
    const int tid = threadIdx.x;
    const int R0 = blockIdx.x * 128;
    const int b  = R0 >> 12;
    const int l0 = R0 & 4095;
    const int tx = tid & 15, ty = tid >> 4;

    float acc[8][8];   // [m][n]
    #pragma unroll
    for (int i = 0; i < 8; ++i)
        #pragma unroll
        for (int j = 0; j < 8; ++j) acc[i][j] = 0.0f;

    for (int kc = 0; kc < 256; kc += 32) {
        #pragma unroll
        for (int it = 0; it < 4; ++it) {
            int idx4 = tid + it * 256;          // 0..1023
            int r = idx4 >> 3, q4 = idx4 & 7;   // r: row 0..127, q4: k-group
            float4 v = *(const float4*)&ybuf[(R0 + r) * 256 + kc + q4 * 4];
            ys[q4*4+0][r] = v.x; ys[q4*4+1][r] = v.y;
            ys[q4*4+2][r] = v.z; ys[q4*4+3][r] = v.w;
            int k = idx4 >> 5, n4 = idx4 & 31;
            float4 w = *(const float4*)&W_out[(kc + k) * 128 + n4 * 4];
            *(float4*)&wt[k][n4 * 4] = w;
        }
        __syncthreads();
        #pragma unroll 2
        for (int k = 0; k < 32; ++k) {
            float4 a0 = *(const float4*)&ys[k][tx * 4];
            float4 a1 = *(const float4*)&ys[k][64 + tx * 4];
            float4 b0 = *(const float4*)&wt[k][ty * 4];
            float4 b1 = *(const float4*)&wt[k][64 + ty * 4];
            float am[8] = {a0.x, a0.y, a0.z, a0.w, a1.x, a1.y, a1.z, a1.w};
            float bn[8] = {b0.x, b0.y, b0.z, b0.w, b1.x, b1.y, b1.z, b1.w};
            #pragma unroll
            for (int i = 0; i < 8; ++i)
                #pragma unroll
                for (int j = 0; j < 8; ++j) acc[i][j] = fmaf(am[i], bn[j], acc[i][j]);
        }
        __syncthreads();
    }
    #pragma unroll
    for (int j = 0; j < 8; ++j) {
        int c = (j < 4) ? (ty * 4 + j) : (64 + ty * 4 + j - 4);
        long base = (long)(b * 128 + c) * 4096 + l0;
        float4 v0 = make_float4(acc[0][j], acc[1][j], acc[2][j], acc[3][j]);
        float4 v1 = make_float4(acc[4][j], acc[5][j], acc[6][j], acc[7][j]);
        *(float4*)&out_mm[base + tx * 4]      = v0;
        *(float4*)&out_mm[base + 64 + tx * 4] = v1;
    }
}

// ---------------------------------------------------------------------------
// K10a: partial sums for GroupNorm. grid 256, block 256
// ---------------------------------------------------------------------------
__global__ __launch_bounds__(256) void k10a_gnpart(
    const float* __restrict__ out_mm, float* __restrict__ part)
{
    const int bid = blockIdx.x;
    const int b = bid >> 5, g = (bid >> 3) & 3, s = bid & 7;
    const float* base = out_mm + (b * 128 + g * 32) * 4096 + s * 16384;
    const int tid = threadIdx.x;
    float sum = 0.f, ssq = 0.f;
    #pragma unroll 4
    for (int it = 0; it < 16; ++it) {
        float4 v = *(const float4*)&base[(tid + it * 256) * 4];
        sum += v.x + v.y + v.z + v.w;
        ssq += v.x*v.x + v.y*v.y + v.z*v.z + v.w*v.w;
    }
    #pragma unroll
    for (int off = 32; off > 0; off >>= 1) {
        sum += __shfl_down(sum, off, 64);
        ssq += __shfl_down(ssq, off, 64);
    }
    __shared__ float ls[8];
    const int wid = tid >> 6, lane = tid & 63;
    if (lane == 0) { ls[wid * 2] = sum; ls[wid * 2 + 1] = ssq; }
    __syncthreads();
    if (tid == 0) {
        float S = ls[0] + ls[2] + ls[4] + ls[6];
        float Q = ls[1] + ls[3] + ls[5] + ls[7];
        part[bid * 2]     = S;
        part[bid * 2 + 1] = Q;
    }
}

// K10b: finalize mean / rsqrt(var+eps) per (b,g). grid 1, block 64
__global__ void k10b_gnstat(const float* __restrict__ part, float* __restrict__ stat)
{
    const int tid = threadIdx.x;
    if (tid < 32) {
        float S = 0.f, Q = 0.f;
        for (int s = 0; s < 8; ++s) {
            S += part[(tid * 8 + s) * 2];
            Q += part[(tid * 8 + s) * 2 + 1];
        }
        const float inv_n = 1.0f / 131072.0f;
        float mean = S * inv_n;
        float var  = Q * inv_n - mean * mean;
        stat[tid * 2]     = mean;
        stat[tid * 2 + 1] = rsqrtf(var + 1e-5f);
    }
}

// K10c: apply GN + silu + residual. grid 4096, block 256
__global__ __launch_bounds__(256) void k10c_apply(
    const float* __restrict__ out_mm, const float* __restrict__ stat,
    const float* __restrict__ gamma, const float* __restrict__ beta,
    const float* __restrict__ x_hsi, float* __restrict__ out)
{
    const int idx4 = blockIdx.x * 256 + threadIdx.x;
    const int flat = idx4 * 4;
    const int c = (flat >> 12) & 127;
    const int b = flat >> 19;
    const int g = c >> 5;
    const float mean = stat[(b * 4 + g) * 2];
    const float inv  = stat[(b * 4 + g) * 2 + 1];
    const float ga = gamma[c], be = beta[c];
    float4 v = *(const float4*)&out_mm[flat];
    float4 r = *(const float4*)&x_hsi[flat];
    float o[4];
    float vv[4] = {v.x, v.y, v.z, v.w};
    float rr[4] = {r.x, r.y, r.z, r.w};
    #pragma unroll
    for (int q = 0; q < 4; ++q) {
        float xn = (vv[q] - mean) * inv;
        float gv = xn * ga + be;
        o[q] = silu_fast(gv) + rr[q];
    }
    *(float4*)&out[flat] = make_float4(o[0], o[1], o[2], o[3]);
}

// ---------------------------------------------------------------------------
extern "C" void kernel_launch(void* const* d_in, const int* in_sizes, int n_in,
                              void* d_out, int out_size, void* d_ws, size_t ws_size,
                              hipStream_t stream)
{
    const float* x_hsi  = (const float*)d_in[0];
    const float* W_in   = (const float*)d_in[1];
    const float* conv_w = (const float*)d_in[2];
    const float* conv_b = (const float*)d_in[3];
    const float* W_x    = (const float*)d_in[4];
    const float* W_dt   = (const float*)d_in[5];
    const float* b_dt   = (const float*)d_in[6];
    const float* A_log  = (const float*)d_in[7];
    const float* Dv     = (const float*)d_in[8];
    const float* W_out  = (const float*)d_in[9];
    const float* gnw    = (const float*)d_in[10];
    const float* gnb    = (const float*)d_in[11];

    float* ws = (float*)d_ws;
    float* xh_raw = ws + 0;            // 8,388,608
    float* zy     = ws + 8388608;      // 8,388,608  z_silu -> y (in-place)
    float* out_mm = ws + 16777216;     // 4,194,304
    float* xdbl   = ws + 20971520;     // 1,310,720
    float* hx     = ws + 22282240;     // 4,194,304  hend -> hin (in-place)
    float* Pp     = ws + 26476544;     // 4,194,304
    float* part   = ws + 30670848;     // 512
    float* stat   = ws + 30671360;     // 64
    float* outp   = (float*)d_out;

    k1_gemm_in<<<dim3(256, 4), 256, 0, stream>>>(x_hsi, W_in, xh_raw, zy);
    k4_xdbl<<<256, 256, 0, stream>>>(xh_raw, conv_w, conv_b, W_x, xdbl);
    k6_scan1<<<dim3(NCH, BATCH), 256, 0, stream>>>(xh_raw, xdbl, conv_w, conv_b,
                                                   W_dt, b_dt, A_log, hx, Pp);
    k7_combine<<<128, 256, 0, stream>>>(Pp, hx);
    k8_scan2<<<dim3(NCH, BATCH), 256, 0, stream>>>(xh_raw, xdbl, conv_w, conv_b,
                                                   W_dt, b_dt, A_log, Dv, hx, zy);
    k9_gemm_out<<<256, 256, 0, stream>>>(zy, W_out, out_mm);
    k10a_gnpart<<<256, 256, 0, stream>>>(out_mm, part);
    k10b_gnstat<<<1, 64, 0, stream>>>(part, stat);
    k10c_apply<<<4096, 256, 0, stream>>>(out_mm, stat, gnw, gnb, x_hsi, outp);
}

// Round 5
// 247.718 us; speedup vs baseline: 1.7075x; 1.1662x over previous
//
#include <hip/hip_runtime.h>
#include <math.h>

// Problem constants
#define BATCH   8
#define LSEQ    4096      // 64*64
#define CMODEL  128
#define DIN     256
#define NSTATE  16
#define RRANK   8
#define NCH     128       // chunks per sequence
#define TCH     32        // timesteps per chunk (NCH*TCH == LSEQ)

typedef __attribute__((ext_vector_type(8))) short short8;
typedef __attribute__((ext_vector_type(4))) float f32x4;

__device__ __forceinline__ float sigmoid_fast(float x) {
    return __builtin_amdgcn_rcpf(1.0f + __expf(-x));
}
__device__ __forceinline__ float silu_fast(float x) { return x * sigmoid_fast(x); }
__device__ __forceinline__ float softplus_fast(float x) {
    return fmaxf(x, 0.0f) + __logf(1.0f + __expf(-fabsf(x)));
}
__device__ __forceinline__ unsigned short f2bf(float f) {
    unsigned u = __float_as_uint(f);
    return (unsigned short)((u + 0x7FFFu + ((u >> 16) & 1u)) >> 16);   // RNE
}
__device__ __forceinline__ unsigned long long pack4bf(float a, float b, float c, float d) {
    return (unsigned long long)f2bf(a)
         | ((unsigned long long)f2bf(b) << 16)
         | ((unsigned long long)f2bf(c) << 32)
         | ((unsigned long long)f2bf(d) << 48);
}

// dA[n] = exp(dtv*A[n]); A[n] == (n+1)*A[0] fast path: 1 exp + mul chain.
__device__ __forceinline__ void dA_powers(float dtv, const float* A, bool fast,
                                          float* dA)
{
    if (fast) {
        float e1 = __expf(dtv * A[0]);
        float e2 = e1 * e1;
        float e4 = e2 * e2;
        float e8 = e4 * e4;
        dA[0] = e1;        dA[1] = e2;        dA[2] = e2 * e1;   dA[3] = e4;
        dA[4] = e4 * e1;   dA[5] = e4 * e2;   dA[6] = e4 * dA[2]; dA[7] = e8;
        dA[8] = e8 * e1;   dA[9] = e8 * e2;   dA[10] = e8 * dA[2]; dA[11] = e8 * e4;
        dA[12] = e8 * dA[4]; dA[13] = e8 * dA[5]; dA[14] = e8 * dA[6]; dA[15] = e8 * e8;
    } else {
        #pragma unroll
        for (int n = 0; n < 16; ++n) dA[n] = __expf(dtv * A[n]);
    }
}

#define LSTR 80   // LDS row stride (bf16 units): 64 data + 16 pad, uniform banks

// ---------------------------------------------------------------------------
// K1 (MFMA bf16): xz = x @ W_in. 128(l) x 128(j) tile, K=128 in chunks of 64.
// A[m=l][k=c] <- x_hsi[b,c,l] (transposed stage); B[n=j][k=c] <- W_in[c,j]
// (transposed stage). 4 waves x 64x64 quadrant, 4x4 tiles of 16x16x32.
// grid (256, 4), block 256
// ---------------------------------------------------------------------------
__global__ __launch_bounds__(256) void k1_gemm_in(
    const float* __restrict__ x_hsi, const float* __restrict__ W_in,
    float* __restrict__ xh_raw, float* __restrict__ z_silu)
{
    __shared__ __align__(16) unsigned short Abf[128 * LSTR];
    __shared__ __align__(16) unsigned short Bbf[128 * LSTR];
    const int tid = threadIdx.x;
    const int R0  = blockIdx.x * 128;         // global row (b*L + l)
    const int b   = R0 >> 12;
    const int l0  = R0 & 4095;
    const int j0  = blockIdx.y * 128;

    const int w    = tid >> 6;
    const int lane = tid & 63;
    const int lm   = lane & 15;
    const int q    = lane >> 4;
    const int mbase = (w & 1) * 64;           // l-quadrant
    const int nbase = (w >> 1) * 64;          // j-quadrant

    f32x4 acc[4][4];
    #pragma unroll
    for (int i = 0; i < 4; ++i)
        #pragma unroll
        for (int j = 0; j < 4; ++j) acc[i][j] = (f32x4){0.f, 0.f, 0.f, 0.f};

    const int cq = tid & 15;                  // k-quad within chunk (16 x 4 = 64)
    const int rq0 = tid >> 4;                 // row-quad base (16; +16 iter)

    for (int kc = 0; kc < 128; kc += 64) {
        __syncthreads();
        // stage A: x[c][l] -> Abf[l][c_local]  (4c x 4l per thread-slot)
        #pragma unroll
        for (int it = 0; it < 2; ++it) {
            int lq = rq0 + it * 16;           // 0..31
            float v[4][4];
            #pragma unroll
            for (int t = 0; t < 4; ++t) {
                float4 f = *(const float4*)&x_hsi[((b * 128 + kc + cq * 4 + t) << 12) + l0 + lq * 4];
                v[t][0] = f.x; v[t][1] = f.y; v[t][2] = f.z; v[t][3] = f.w;
            }
            #pragma unroll
            for (int i = 0; i < 4; ++i)
                *(unsigned long long*)&Abf[(lq * 4 + i) * LSTR + cq * 4] =
                    pack4bf(v[0][i], v[1][i], v[2][i], v[3][i]);
        }
        // stage B: W_in[c][j] -> Bbf[j][c_local]
        #pragma unroll
        for (int it = 0; it < 2; ++it) {
            int jq = rq0 + it * 16;
            float v[4][4];
            #pragma unroll
            for (int t = 0; t < 4; ++t) {
                float4 f = *(const float4*)&W_in[(kc + cq * 4 + t) * 512 + j0 + jq * 4];
                v[t][0] = f.x; v[t][1] = f.y; v[t][2] = f.z; v[t][3] = f.w;
            }
            #pragma unroll
            for (int i = 0; i < 4; ++i)
                *(unsigned long long*)&Bbf[(jq * 4 + i) * LSTR + cq * 4] =
                    pack4bf(v[0][i], v[1][i], v[2][i], v[3][i]);
        }
        __syncthreads();
        #pragma unroll
        for (int kt = 0; kt < 2; ++kt) {
            short8 af[4], bfr[4];
            #pragma unroll
            for (int mt = 0; mt < 4; ++mt)
                af[mt] = *(const short8*)&Abf[(mbase + mt * 16 + lm) * LSTR + kt * 32 + q * 8];
            #pragma unroll
            for (int nt = 0; nt < 4; ++nt)
                bfr[nt] = *(const short8*)&Bbf[(nbase + nt * 16 + lm) * LSTR + kt * 32 + q * 8];
            #pragma unroll
            for (int mt = 0; mt < 4; ++mt)
                #pragma unroll
                for (int nt = 0; nt < 4; ++nt)
                    acc[mt][nt] = __builtin_amdgcn_mfma_f32_16x16x32_bf16(
                        af[mt], bfr[nt], acc[mt][nt], 0, 0, 0);
        }
    }

    const bool is_xh = (j0 < 256);
    #pragma unroll
    for (int mt = 0; mt < 4; ++mt) {
        #pragma unroll
        for (int r = 0; r < 4; ++r) {
            int row = R0 + mbase + mt * 16 + q * 4 + r;
            #pragma unroll
            for (int nt = 0; nt < 4; ++nt) {
                int col = j0 + nbase + nt * 16 + lm;
                float val = acc[mt][nt][r];
                if (is_xh) xh_raw[row * 256 + col] = val;
                else       z_silu[row * 256 + col - 256] = silu_fast(val);
            }
        }
    }
}

// ---------------------------------------------------------------------------
// K4: xdbl = conv_silu(xh) @ W_x tiled GEMM (fp32, unchanged).
// grid 256, block 256
// ---------------------------------------------------------------------------
__global__ __launch_bounds__(256) void k4_xdbl(
    const float* __restrict__ xh_raw, const float* __restrict__ conv_w,
    const float* __restrict__ conv_b, const float* __restrict__ W_x,
    float* __restrict__ xdbl)
{
    __shared__ float xcs[128][68];
    __shared__ float wxs[64 * 40];
    __shared__ float cw0[256], cw1[256], cbs[256];
    const int tid = threadIdx.x;
    cw0[tid] = conv_w[2 * tid];
    cw1[tid] = conv_w[2 * tid + 1];
    cbs[tid] = conv_b[tid];

    const int R0 = blockIdx.x * 128;
    const int tc = tid & 7;
    const int tr = tid >> 3;

    float acc[4][5];
    #pragma unroll
    for (int i = 0; i < 4; ++i)
        #pragma unroll
        for (int j = 0; j < 5; ++j) acc[i][j] = 0.0f;

    for (int kc = 0; kc < 256; kc += 64) {
        __syncthreads();
        #pragma unroll
        for (int it = 0; it < 3; ++it) {
            int i4 = tid + it * 256;
            if (i4 < 640) ((float4*)wxs)[i4] = ((const float4*)&W_x[kc * 40])[i4];
        }
        #pragma unroll
        for (int it = 0; it < 8; ++it) {
            int idx = tid + it * 256;
            int r = idx >> 4, qq = idx & 15;
            int row = R0 + r;
            float4 cur = *(const float4*)&xh_raw[row * 256 + kc + qq * 4];
            float4 prv = make_float4(0.f, 0.f, 0.f, 0.f);
            if ((row & 4095) != 0)
                prv = *(const float4*)&xh_raw[(row - 1) * 256 + kc + qq * 4];
            int d = kc + qq * 4;
            float4 o;
            o.x = silu_fast(prv.x * cw0[d+0] + cur.x * cw1[d+0] + cbs[d+0]);
            o.y = silu_fast(prv.y * cw0[d+1] + cur.y * cw1[d+1] + cbs[d+1]);
            o.z = silu_fast(prv.z * cw0[d+2] + cur.z * cw1[d+2] + cbs[d+2]);
            o.w = silu_fast(prv.w * cw0[d+3] + cur.w * cw1[d+3] + cbs[d+3]);
            *(float4*)&xcs[r][qq * 4] = o;
        }
        __syncthreads();
        #pragma unroll 2
        for (int k = 0; k < 64; ++k) {
            float wv[5];
            #pragma unroll
            for (int j = 0; j < 5; ++j) wv[j] = wxs[k * 40 + tc * 5 + j];
            #pragma unroll
            for (int i = 0; i < 4; ++i) {
                float a = xcs[tr * 4 + i][k];
                #pragma unroll
                for (int j = 0; j < 5; ++j) acc[i][j] = fmaf(a, wv[j], acc[i][j]);
            }
        }
    }
    #pragma unroll
    for (int i = 0; i < 4; ++i) {
        int row = R0 + tr * 4 + i;
        #pragma unroll
        for (int j = 0; j < 5; ++j) xdbl[row * 40 + tc * 5 + j] = acc[i][j];
    }
}

// ---------------------------------------------------------------------------
// Scan pass 1: local h + decay product P. grid (NCH, BATCH), block 256
// ---------------------------------------------------------------------------
__global__ __launch_bounds__(256) void k6_scan1(
    const float* __restrict__ xh_raw, const float* __restrict__ xdbl,
    const float* __restrict__ conv_w, const float* __restrict__ conv_b,
    const float* __restrict__ W_dt, const float* __restrict__ b_dt,
    const float* __restrict__ A_log,
    float* __restrict__ hend, float* __restrict__ Pprod)
{
    __shared__ float xd[TCH * 40];
    const int d = threadIdx.x;
    const int chunk = blockIdx.x;
    const int b = blockIdx.y;
    const int t0 = b * LSEQ + chunk * TCH;

    {
        const float4* src = (const float4*)&xdbl[t0 * 40];
        if (d < 256) ((float4*)xd)[d] = src[d];
        int i2 = d + 256;
        if (i2 < 320) ((float4*)xd)[i2] = src[i2];
    }

    float A[16];
    #pragma unroll
    for (int qq = 0; qq < 4; ++qq) {
        float4 al = *(const float4*)&A_log[d * 16 + qq * 4];
        A[qq*4+0] = -__expf(al.x); A[qq*4+1] = -__expf(al.y);
        A[qq*4+2] = -__expf(al.z); A[qq*4+3] = -__expf(al.w);
    }
    bool fast = true;
    #pragma unroll
    for (int n = 1; n < 16; ++n)
        fast = fast && (fabsf(A[n] - (n + 1) * A[0]) <= 1e-4f * fabsf(A[n]) + 1e-7f);

    float wdt[8];
    #pragma unroll
    for (int r = 0; r < 8; ++r) wdt[r] = W_dt[r * 256 + d];
    const float bdt = b_dt[d];
    const float w0 = conv_w[2 * d], w1 = conv_w[2 * d + 1], cb = conv_b[d];

    float h[16];
    #pragma unroll
    for (int n = 0; n < 16; ++n) h[n] = 0.f;
    float dtsum = 0.f;

    float prev = (chunk > 0) ? xh_raw[(t0 - 1) * 256 + d] : 0.f;
    __syncthreads();

    #pragma unroll 2
    for (int tt = 0; tt < TCH; ++tt) {
        const int row = t0 + tt;
        float cur = xh_raw[row * 256 + d];
        float xcv = silu_fast(prev * w0 + cur * w1 + cb);
        prev = cur;

        const float* xr = &xd[tt * 40];
        float dl[8];
        *(float4*)&dl[0] = *(const float4*)&xr[0];
        *(float4*)&dl[4] = *(const float4*)&xr[4];
        float dtr = bdt;
        #pragma unroll
        for (int r = 0; r < 8; ++r) dtr = fmaf(dl[r], wdt[r], dtr);
        float dtv = softplus_fast(dtr);
        dtsum += dtv;

        float Bt[16];
        #pragma unroll
        for (int qq = 0; qq < 4; ++qq)
            *(float4*)&Bt[qq * 4] = *(const float4*)&xr[8 + qq * 4];

        float dA[16];
        dA_powers(dtv, A, fast, dA);
        float dtx = dtv * xcv;
        #pragma unroll
        for (int n = 0; n < 16; ++n)
            h[n] = fmaf(dA[n], h[n], dtx * Bt[n]);
    }

    float P[16];
    dA_powers(dtsum, A, fast, P);
    const int base = ((b * NCH + chunk) * 256 + d) * 16;
    #pragma unroll
    for (int qq = 0; qq < 4; ++qq) {
        *(float4*)&hend[base + qq * 4] = make_float4(h[qq*4], h[qq*4+1], h[qq*4+2], h[qq*4+3]);
        *(float4*)&Pprod[base + qq * 4] = make_float4(P[qq*4], P[qq*4+1], P[qq*4+2], P[qq*4+3]);
    }
}

// ---------------------------------------------------------------------------
// Scan pass 2: sequential combine; hx: hend -> hin in-place. grid 128x256
// ---------------------------------------------------------------------------
__global__ __launch_bounds__(256) void k7_combine(
    const float* __restrict__ Pp, float* __restrict__ hx)
{
    const int idx = blockIdx.x * 256 + threadIdx.x;   // b*4096 + d*16 + n
    const int b = idx >> 12;
    const int rem = idx & 4095;
    int o = ((b * NCH) << 12) + rem;
    float h = 0.f;
    float P = Pp[o], E = hx[o];
    for (int c = 0; c < NCH; ++c) {
        int on = o + 4096;
        float Pn = 0.f, En = 0.f;
        if (c < NCH - 1) { Pn = Pp[on]; En = hx[on]; }
        hx[o] = h;
        h = fmaf(P, h, E);
        P = Pn; E = En; o = on;
    }
}

// ---------------------------------------------------------------------------
// Scan pass 3: replay with h_in, y = (scan + xc*D) * z_silu, in-place zy.
// grid (NCH, BATCH), block 256
// ---------------------------------------------------------------------------
__global__ __launch_bounds__(256) void k8_scan2(
    const float* __restrict__ xh_raw, const float* __restrict__ xdbl,
    const float* __restrict__ conv_w, const float* __restrict__ conv_b,
    const float* __restrict__ W_dt, const float* __restrict__ b_dt,
    const float* __restrict__ A_log, const float* __restrict__ Dvec,
    const float* __restrict__ hin, float* __restrict__ zy)
{
    __shared__ float xd[TCH * 40];
    const int d = threadIdx.x;
    const int chunk = blockIdx.x;
    const int b = blockIdx.y;
    const int t0 = b * LSEQ + chunk * TCH;

    {
        const float4* src = (const float4*)&xdbl[t0 * 40];
        if (d < 256) ((float4*)xd)[d] = src[d];
        int i2 = d + 256;
        if (i2 < 320) ((float4*)xd)[i2] = src[i2];
    }

    float A[16];
    #pragma unroll
    for (int qq = 0; qq < 4; ++qq) {
        float4 al = *(const float4*)&A_log[d * 16 + qq * 4];
        A[qq*4+0] = -__expf(al.x); A[qq*4+1] = -__expf(al.y);
        A[qq*4+2] = -__expf(al.z); A[qq*4+3] = -__expf(al.w);
    }
    bool fast = true;
    #pragma unroll
    for (int n = 1; n < 16; ++n)
        fast = fast && (fabsf(A[n] - (n + 1) * A[0]) <= 1e-4f * fabsf(A[n]) + 1e-7f);

    float wdt[8];
    #pragma unroll
    for (int r = 0; r < 8; ++r) wdt[r] = W_dt[r * 256 + d];
    const float bdt = b_dt[d];
    const float w0 = conv_w[2 * d], w1 = conv_w[2 * d + 1], cb = conv_b[d];
    const float Dd = Dvec[d];

    float h[16];
    const int hbase = ((b * NCH + chunk) * 256 + d) * 16;
    #pragma unroll
    for (int qq = 0; qq < 4; ++qq) {
        float4 hv = *(const float4*)&hin[hbase + qq * 4];
        h[qq*4+0] = hv.x; h[qq*4+1] = hv.y; h[qq*4+2] = hv.z; h[qq*4+3] = hv.w;
    }

    float prev = (chunk > 0) ? xh_raw[(t0 - 1) * 256 + d] : 0.f;
    __syncthreads();

    #pragma unroll 2
    for (int tt = 0; tt < TCH; ++tt) {
        const int row = t0 + tt;
        float cur = xh_raw[row * 256 + d];
        float xcv = silu_fast(prev * w0 + cur * w1 + cb);
        prev = cur;

        const float* xr = &xd[tt * 40];
        float dl[8];
        *(float4*)&dl[0] = *(const float4*)&xr[0];
        *(float4*)&dl[4] = *(const float4*)&xr[4];
        float dtr = bdt;
        #pragma unroll
        for (int r = 0; r < 8; ++r) dtr = fmaf(dl[r], wdt[r], dtr);
        float dtv = softplus_fast(dtr);

        float Bt[16], Ct[16];
        #pragma unroll
        for (int qq = 0; qq < 4; ++qq) {
            *(float4*)&Bt[qq * 4] = *(const float4*)&xr[8 + qq * 4];
            *(float4*)&Ct[qq * 4] = *(const float4*)&xr[24 + qq * 4];
        }

        float dA[16];
        dA_powers(dtv, A, fast, dA);
        float dtx = dtv * xcv;
        float yv = 0.f;
        #pragma unroll
        for (int n = 0; n < 16; ++n) {
            h[n] = fmaf(dA[n], h[n], dtx * Bt[n]);
            yv = fmaf(h[n], Ct[n], yv);
        }
        yv = fmaf(Dd, xcv, yv);
        const int oidx = row * 256 + d;
        float zs = zy[oidx];
        zy[oidx] = yv * zs;
    }
}

// ---------------------------------------------------------------------------
// K9 (MFMA bf16): out_mm[b,c,l] = sum_k y[b,l,k] * W_out[k,c].
// M=c (A[m=c][k] <- W_out transposed), N=l (B[n=l][k] <- y, no transpose).
// 128(c) x 128(l) tile, K=256 in chunks of 64. grid 256, block 256
// ---------------------------------------------------------------------------
__global__ __launch_bounds__(256) void k9_gemm_out(
    const float* __restrict__ ybuf, const float* __restrict__ W_out,
    float* __restrict__ out_mm)
{
    __shared__ __align__(16) unsigned short Abf[128 * LSTR];   // rows = c
    __shared__ __align__(16) unsigned short Bbf[128 * LSTR];   // rows = l
    const int tid = threadIdx.x;
    const int R0 = blockIdx.x * 128;
    const int b  = R0 >> 12;
    const int l0 = R0 & 4095;

    const int w    = tid >> 6;
    const int lane = tid & 63;
    const int lm   = lane & 15;
    const int q    = lane >> 4;
    const int mbase = (w & 1) * 64;           // c-quadrant
    const int nbase = (w >> 1) * 64;          // l-quadrant

    f32x4 acc[4][4];
    #pragma unroll
    for (int i = 0; i < 4; ++i)
        #pragma unroll
        for (int j = 0; j < 4; ++j) acc[i][j] = (f32x4){0.f, 0.f, 0.f, 0.f};

    const int kq  = tid & 15;                 // k-quad in chunk
    const int rq0 = tid >> 4;

    for (int kc = 0; kc < 256; kc += 64) {
        __syncthreads();
        // stage A: W_out[k][c] -> Abf[c][k_local]  (4k x 4c per slot)
        #pragma unroll
        for (int it = 0; it < 2; ++it) {
            int crq = rq0 + it * 16;          // 0..31
            float v[4][4];
            #pragma unroll
            for (int t = 0; t < 4; ++t) {
                float4 f = *(const float4*)&W_out[(kc + kq * 4 + t) * 128 + crq * 4];
                v[t][0] = f.x; v[t][1] = f.y; v[t][2] = f.z; v[t][3] = f.w;
            }
            #pragma unroll
            for (int i = 0; i < 4; ++i)
                *(unsigned long long*)&Abf[(crq * 4 + i) * LSTR + kq * 4] =
                    pack4bf(v[0][i], v[1][i], v[2][i], v[3][i]);
        }
        // stage B: y[l][k] -> Bbf[l][k_local] (no transpose)
        #pragma unroll
        for (int it = 0; it < 8; ++it) {
            int lrow = rq0 + it * 16;         // 0..127
            float4 f = *(const float4*)&ybuf[(R0 + lrow) * 256 + kc + kq * 4];
            *(unsigned long long*)&Bbf[lrow * LSTR + kq * 4] =
                pack4bf(f.x, f.y, f.z, f.w);
        }
        __syncthreads();
        #pragma unroll
        for (int kt = 0; kt < 2; ++kt) {
            short8 af[4], bfr[4];
            #pragma unroll
            for (int mt = 0; mt < 4; ++mt)
                af[mt] = *(const short8*)&Abf[(mbase + mt * 16 + lm) * LSTR + kt * 32 + q * 8];
            #pragma unroll
            for (int nt = 0; nt < 4; ++nt)
                bfr[nt] = *(const short8*)&Bbf[(nbase + nt * 16 + lm) * LSTR + kt * 32 + q * 8];
            #pragma unroll
            for (int mt = 0; mt < 4; ++mt)
                #pragma unroll
                for (int nt = 0; nt < 4; ++nt)
                    acc[mt][nt] = __builtin_amdgcn_mfma_f32_16x16x32_bf16(
                        af[mt], bfr[nt], acc[mt][nt], 0, 0, 0);
        }
    }

    #pragma unroll
    for (int mt = 0; mt < 4; ++mt) {
        #pragma unroll
        for (int r = 0; r < 4; ++r) {
            int c = mbase + mt * 16 + q * 4 + r;
            long base = (long)(b * 128 + c) * 4096 + l0;
            #pragma unroll
            for (int nt = 0; nt < 4; ++nt)
                out_mm[base + nbase + nt * 16 + lm] = acc[mt][nt][r];
        }
    }
}

// ---------------------------------------------------------------------------
// K10a: partial sums for GroupNorm. grid 256, block 256
// ---------------------------------------------------------------------------
__global__ __launch_bounds__(256) void k10a_gnpart(
    const float* __restrict__ out_mm, float* __restrict__ part)
{
    const int bid = blockIdx.x;
    const int b = bid >> 5, g = (bid >> 3) & 3, s = bid & 7;
    const float* base = out_mm + (b * 128 + g * 32) * 4096 + s * 16384;
    const int tid = threadIdx.x;
    float sum = 0.f, ssq = 0.f;
    #pragma unroll 4
    for (int it = 0; it < 16; ++it) {
        float4 v = *(const float4*)&base[(tid + it * 256) * 4];
        sum += v.x + v.y + v.z + v.w;
        ssq += v.x*v.x + v.y*v.y + v.z*v.z + v.w*v.w;
    }
    #pragma unroll
    for (int off = 32; off > 0; off >>= 1) {
        sum += __shfl_down(sum, off, 64);
        ssq += __shfl_down(ssq, off, 64);
    }
    __shared__ float ls[8];
    const int wid = tid >> 6, lane = tid & 63;
    if (lane == 0) { ls[wid * 2] = sum; ls[wid * 2 + 1] = ssq; }
    __syncthreads();
    if (tid == 0) {
        float S = ls[0] + ls[2] + ls[4] + ls[6];
        float Q = ls[1] + ls[3] + ls[5] + ls[7];
        part[bid * 2]     = S;
        part[bid * 2 + 1] = Q;
    }
}

// K10b: finalize mean / rsqrt(var+eps) per (b,g). grid 1, block 64
__global__ void k10b_gnstat(const float* __restrict__ part, float* __restrict__ stat)
{
    const int tid = threadIdx.x;
    if (tid < 32) {
        float S = 0.f, Q = 0.f;
        for (int s = 0; s < 8; ++s) {
            S += part[(tid * 8 + s) * 2];
            Q += part[(tid * 8 + s) * 2 + 1];
        }
        const float inv_n = 1.0f / 131072.0f;
        float mean = S * inv_n;
        float var  = Q * inv_n - mean * mean;
        stat[tid * 2]     = mean;
        stat[tid * 2 + 1] = rsqrtf(var + 1e-5f);
    }
}

// K10c: apply GN + silu + residual. grid 4096, block 256
__global__ __launch_bounds__(256) void k10c_apply(
    const float* __restrict__ out_mm, const float* __restrict__ stat,
    const float* __restrict__ gamma, const float* __restrict__ beta,
    const float* __restrict__ x_hsi, float* __restrict__ out)
{
    const int idx4 = blockIdx.x * 256 + threadIdx.x;
    const int flat = idx4 * 4;
    const int c = (flat >> 12) & 127;
    const int b = flat >> 19;
    const int g = c >> 5;
    const float mean = stat[(b * 4 + g) * 2];
    const float inv  = stat[(b * 4 + g) * 2 + 1];
    const float ga = gamma[c], be = beta[c];
    float4 v = *(const float4*)&out_mm[flat];
    float4 r = *(const float4*)&x_hsi[flat];
    float o[4];
    float vv[4] = {v.x, v.y, v.z, v.w};
    float rr[4] = {r.x, r.y, r.z, r.w};
    #pragma unroll
    for (int qq = 0; qq < 4; ++qq) {
        float xn = (vv[qq] - mean) * inv;
        float gv = xn * ga + be;
        o[qq] = silu_fast(gv) + rr[qq];
    }
    *(float4*)&out[flat] = make_float4(o[0], o[1], o[2], o[3]);
}

// ---------------------------------------------------------------------------
extern "C" void kernel_launch(void* const* d_in, const int* in_sizes, int n_in,
                              void* d_out, int out_size, void* d_ws, size_t ws_size,
                              hipStream_t stream)
{
    const float* x_hsi  = (const float*)d_in[0];
    const float* W_in   = (const float*)d_in[1];
    const float* conv_w = (const float*)d_in[2];
    const float* conv_b = (const float*)d_in[3];
    const float* W_x    = (const float*)d_in[4];
    const float* W_dt   = (const float*)d_in[5];
    const float* b_dt   = (const float*)d_in[6];
    const float* A_log  = (const float*)d_in[7];
    const float* Dv     = (const float*)d_in[8];
    const float* W_out  = (const float*)d_in[9];
    const float* gnw    = (const float*)d_in[10];
    const float* gnb    = (const float*)d_in[11];

    float* ws = (float*)d_ws;
    float* xh_raw = ws + 0;            // 8,388,608
    float* zy     = ws + 8388608;      // 8,388,608  z_silu -> y (in-place)
    float* out_mm = ws + 16777216;     // 4,194,304
    float* xdbl   = ws + 20971520;     // 1,310,720
    float* hx     = ws + 22282240;     // 4,194,304  hend -> hin (in-place)
    float* Pp     = ws + 26476544;     // 4,194,304
    float* part   = ws + 30670848;     // 512
    float* stat   = ws + 30671360;     // 64
    float* outp   = (float*)d_out;

    k1_gemm_in<<<dim3(256, 4), 256, 0, stream>>>(x_hsi, W_in, xh_raw, zy);
    k4_xdbl<<<256, 256, 0, stream>>>(xh_raw, conv_w, conv_b, W_x, xdbl);
    k6_scan1<<<dim3(NCH, BATCH), 256, 0, stream>>>(xh_raw, xdbl, conv_w, conv_b,
                                                   W_dt, b_dt, A_log, hx, Pp);
    k7_combine<<<128, 256, 0, stream>>>(Pp, hx);
    k8_scan2<<<dim3(NCH, BATCH), 256, 0, stream>>>(xh_raw, xdbl, conv_w, conv_b,
                                                   W_dt, b_dt, A_log, Dv, hx, zy);
    k9_gemm_out<<<256, 256, 0, stream>>>(zy, W_out, out_mm);
    k10a_gnpart<<<256, 256, 0, stream>>>(out_mm, part);
    k10b_gnstat<<<1, 64, 0, stream>>>(part, stat);
    k10c_apply<<<4096, 256, 0, stream>>>(out_mm, stat, gnw, gnb, x_hsi, outp);
}